// Round 6
// baseline (2155.416 us; speedup 1.0000x reference)
//
#include <hip/hip_runtime.h>

#define Vv 32000
#define Ee 256
#define Hh 512
#define Ll 128
#define Bb 16
#define Tt 128
#define G3 1536   // 3*H
#define NWG 64    // persistent scan workgroups
#define NPAIR (Bb * Hh)   // 8192 h elements

typedef __attribute__((ext_vector_type(8))) short short8;
typedef __attribute__((ext_vector_type(4))) float f32x4;

__device__ __forceinline__ float sigmoidf_(float x) { return 1.f / (1.f + __expf(-x)); }

// f32 -> bf16 round-to-nearest-even
__device__ __forceinline__ unsigned short f2bf(float f) {
  unsigned int u = __float_as_uint(f);
  u = (u + 0x7fffu + ((u >> 16) & 1u)) >> 16;
  return (unsigned short)u;
}

// zero outputs[:, 0, :]
__global__ void k_zero_first(float* __restrict__ out) {
  int idx = blockIdx.x * 256 + threadIdx.x;
  if (idx < Bb * Vv) {
    int b = idx / Vv, v = idx % Vv;
    out[(size_t)b * Tt * Vv + v] = 0.f;
  }
}

// init epoch-tagged pair buffers: enc buf0 (0,ep=0), enc buf1 (0,~0), dec buf1 (0,~0)
__global__ void k_init_pairs(uint2* __restrict__ encp, uint2* __restrict__ decp) {
  int idx = blockIdx.x * 256 + threadIdx.x;
  if (idx < NPAIR) {
    encp[idx] = make_uint2(0u, 0u);
  } else if (idx < 2 * NPAIR) {
    encp[idx] = make_uint2(0u, 0xFFFFFFFFu);
  } else if (idx < 3 * NPAIR) {
    decp[idx - NPAIR] = make_uint2(0u, 0xFFFFFFFFu);  // dec buf1
  }
}

// ---------------- f32 -> bf16 bulk convert ----------------
__global__ void k_cvt_bf16(const float* __restrict__ in, unsigned short* __restrict__ out,
                           int n4) {
  int i = blockIdx.x * 256 + threadIdx.x;
  if (i < n4) {
    float4 v = ((const float4*)in)[i];
    ushort4 o;
    o.x = f2bf(v.x); o.y = f2bf(v.y); o.z = f2bf(v.z); o.w = f2bf(v.w);
    ((ushort4*)out)[i] = o;
  }
}

// ---------------- transpose: in [R][C] -> out [C][R] ----------------
__global__ void k_transpose(const float* __restrict__ in, float* __restrict__ out,
                            int R, int C) {
  __shared__ float tile[32][33];
  int c = blockIdx.x * 32 + threadIdx.x;
  int r0 = blockIdx.y * 32;
  for (int i = threadIdx.y; i < 32; i += 8)
    tile[i][threadIdx.x] = in[(size_t)(r0 + i) * C + c];
  __syncthreads();
  int r = r0 + threadIdx.x;
  int c0 = blockIdx.x * 32;
  for (int i = threadIdx.y; i < 32; i += 8)
    out[(size_t)(c0 + i) * R + r] = tile[threadIdx.x][i];
}

// ---------------- gx = emb[x] @ W_ih^T + b_ih ----------------
__global__ void k_gx(const int* __restrict__ x, const float* __restrict__ emb,
                     const float* __restrict__ WihT, const float* __restrict__ b_ih,
                     float* __restrict__ gx) {
  int g = blockIdx.y * 256 + threadIdx.x;
  int mt = blockIdx.x;
  __shared__ float A[16][Ee];
  for (int i = 0; i < 16; i++) {
    int m = mt * 16 + i;
    int t = m >> 4, b = m & 15;
    int tok = x[b * Tt + t];
    A[i][threadIdx.x] = emb[(size_t)tok * Ee + threadIdx.x];
  }
  __syncthreads();
  float acc[16];
  float bg = b_ih[g];
#pragma unroll
  for (int i = 0; i < 16; i++) acc[i] = bg;
#pragma unroll 4
  for (int e = 0; e < Ee; e++) {
    float w = WihT[(size_t)e * G3 + g];
#pragma unroll
    for (int i = 0; i < 16; i++) acc[i] = fmaf(A[i][e], w, acc[i]);
  }
#pragma unroll
  for (int i = 0; i < 16; i++)
    gx[(size_t)(mt * 16 + i) * G3 + g] = acc[i];
}

// ---------------- persistent GRU scan: epoch-tagged single-RT exchange ----------------
// pairs: [2][NPAIR] of (f32 value, u32 epoch). h(s) lives in pairs[s&1] with epoch s.
__global__ void __launch_bounds__(256) k_scan(
    const float* __restrict__ Whh,   // [3H][H]
    const float* __restrict__ bhh,   // [3H]
    const float* __restrict__ gx,    // [nsteps*16][3H]
    uint2* __restrict__ pairs,       // [2][NPAIR]
    unsigned short* __restrict__ hseq,  // [nsteps][16][H] bf16, or nullptr
    int nsteps) {
  __shared__ float h_lds[NPAIR];              // 32 KB
  __shared__ float scratch[4][8][3][Bb];      // 6 KB
  const int tid = threadIdx.x;
  const int wg = blockIdx.x;
  const int jloc = tid & 7;
  const int ks = tid >> 3;    // 0..31
  const int j = wg * 8 + jloc;
  const int k0 = ks * 16;

  // load recurrent weights into registers (once)
  float wr[16], wz[16], wn[16];
  {
    const float4* R = (const float4*)(Whh + (size_t)j * Hh + k0);
    const float4* Z = (const float4*)(Whh + (size_t)(Hh + j) * Hh + k0);
    const float4* N = (const float4*)(Whh + (size_t)(2 * Hh + j) * Hh + k0);
#pragma unroll
    for (int q = 0; q < 4; ++q) {
      float4 a = R[q]; wr[4*q] = a.x; wr[4*q+1] = a.y; wr[4*q+2] = a.z; wr[4*q+3] = a.w;
      float4 b = Z[q]; wz[4*q] = b.x; wz[4*q+1] = b.y; wz[4*q+2] = b.z; wz[4*q+3] = b.w;
      float4 c = N[q]; wn[4*q] = c.x; wn[4*q+1] = c.y; wn[4*q+2] = c.z; wn[4*q+3] = c.w;
    }
  }
  float bhr = 0.f, bhz = 0.f, bhn = 0.f;
  if (tid < 128) { bhr = bhh[j]; bhz = bhh[Hh + j]; bhn = bhh[2 * Hh + j]; }

  // gx for step 0
  float xr = 0.f, xz = 0.f, xn = 0.f;
  if (tid < 128) {
    const float* gp = gx + (size_t)ks * G3 + j;
    xr = gp[0]; xz = gp[Hh]; xn = gp[2 * Hh];
  }

  for (int t = 0; t < nsteps; ++t) {
    // ---- poll + stage h(t): data IS the flag (one LLC RT) ----
    uint4 v[16];
    {
      const uint4* base = (const uint4*)(pairs + (size_t)(t & 1) * NPAIR);
      const unsigned exp_ep = (unsigned)t;
      bool ok = false;
      while (!ok) {
#pragma unroll
        for (int i = 0; i < 16; ++i) {
          const uint4* p = base + tid + 256 * i;
          asm volatile("global_load_dwordx4 %0, %1, off sc1" : "=v"(v[i]) : "v"(p));
        }
        asm volatile("s_waitcnt vmcnt(0)" ::: "memory");
        ok = true;
#pragma unroll
        for (int i = 0; i < 16; ++i)
          ok &= (v[i].y == exp_ep) & (v[i].w == exp_ep);
      }
    }
    __syncthreads();   // previous step's h_lds consumers are done
#pragma unroll
    for (int i = 0; i < 16; ++i) {
      int c = tid + 256 * i;
      h_lds[2 * c] = __uint_as_float(v[i].x);
      h_lds[2 * c + 1] = __uint_as_float(v[i].z);
    }
    __syncthreads();

    float accR[Bb], accZ[Bb], accN[Bb];
#pragma unroll
    for (int b = 0; b < Bb; ++b) { accR[b] = 0.f; accZ[b] = 0.f; accN[b] = 0.f; }
#pragma unroll
    for (int b = 0; b < Bb; ++b) {
      const float4* hp = (const float4*)(h_lds + b * Hh + k0);
#pragma unroll
      for (int q = 0; q < 4; ++q) {
        float4 hv = hp[q];
        accR[b] = fmaf(wr[4*q+0], hv.x, accR[b]);
        accR[b] = fmaf(wr[4*q+1], hv.y, accR[b]);
        accR[b] = fmaf(wr[4*q+2], hv.z, accR[b]);
        accR[b] = fmaf(wr[4*q+3], hv.w, accR[b]);
        accZ[b] = fmaf(wz[4*q+0], hv.x, accZ[b]);
        accZ[b] = fmaf(wz[4*q+1], hv.y, accZ[b]);
        accZ[b] = fmaf(wz[4*q+2], hv.z, accZ[b]);
        accZ[b] = fmaf(wz[4*q+3], hv.w, accZ[b]);
        accN[b] = fmaf(wn[4*q+0], hv.x, accN[b]);
        accN[b] = fmaf(wn[4*q+1], hv.y, accN[b]);
        accN[b] = fmaf(wn[4*q+2], hv.z, accN[b]);
        accN[b] = fmaf(wn[4*q+3], hv.w, accN[b]);
      }
    }
#pragma unroll
    for (int b = 0; b < Bb; ++b) {
      accR[b] += __shfl_xor(accR[b], 8, 64);
      accR[b] += __shfl_xor(accR[b], 16, 64);
      accR[b] += __shfl_xor(accR[b], 32, 64);
      accZ[b] += __shfl_xor(accZ[b], 8, 64);
      accZ[b] += __shfl_xor(accZ[b], 16, 64);
      accZ[b] += __shfl_xor(accZ[b], 32, 64);
      accN[b] += __shfl_xor(accN[b], 8, 64);
      accN[b] += __shfl_xor(accN[b], 16, 64);
      accN[b] += __shfl_xor(accN[b], 32, 64);
    }
    if ((ks & 7) == 0) {
      const int wv = tid >> 6;
#pragma unroll
      for (int b = 0; b < Bb; ++b) {
        scratch[wv][jloc][0][b] = accR[b];
        scratch[wv][jloc][1][b] = accZ[b];
        scratch[wv][jloc][2][b] = accN[b];
      }
    }
    __syncthreads();

    if (tid < 128) {
      const int b = ks;
      float ar = scratch[0][jloc][0][b] + scratch[1][jloc][0][b] +
                 scratch[2][jloc][0][b] + scratch[3][jloc][0][b] + bhr;
      float az = scratch[0][jloc][1][b] + scratch[1][jloc][1][b] +
                 scratch[2][jloc][1][b] + scratch[3][jloc][1][b] + bhz;
      float an = scratch[0][jloc][2][b] + scratch[1][jloc][2][b] +
                 scratch[2][jloc][2][b] + scratch[3][jloc][2][b] + bhn;
      float r = sigmoidf_(xr + ar);
      float u = sigmoidf_(xz + az);
      float n = tanhf(xn + r * an);
      float hold = h_lds[b * Hh + j];
      float hnew = (1.f - u) * n + u * hold;
      // publish (value, epoch t+1) as one 8B coherent store — data is the flag
      uint2 pv;
      pv.x = __float_as_uint(hnew);
      pv.y = (unsigned)(t + 1);
      uint2* dst = pairs + (size_t)((t + 1) & 1) * NPAIR + (b * Hh + j);
      asm volatile("global_store_dwordx2 %0, %1, off sc1" : : "v"(dst), "v"(pv) : "memory");
      if (hseq) hseq[((size_t)t * Bb + b) * Hh + j] = f2bf(hnew);
      // prefetch next step's gx (normal cached loads; latency hides under next poll)
      if (t + 1 < nsteps) {
        const float* gp = gx + (size_t)((t + 1) * Bb + ks) * G3 + j;
        xr = gp[0]; xz = gp[Hh]; xn = gp[2 * Hh];
      }
    }
    // no trailing barrier: next step's poll enforces arrival
  }
}

// ---------------- z = h_last @ fc_enc_W^T + b (reads pair buffer) ----------------
__global__ void k_z(const uint2* __restrict__ hp, const float* __restrict__ W,
                    const float* __restrict__ bias, float* __restrict__ zws,
                    float* __restrict__ zout) {
  int b = blockIdx.x;
  int l = threadIdx.x;  // 128
  __shared__ float hsh[Hh];
  for (int i = threadIdx.x; i < Hh; i += 128)
    hsh[i] = __uint_as_float(hp[b * Hh + i].x);
  __syncthreads();
  float acc = bias[l];
#pragma unroll 4
  for (int k = 0; k < Hh; k++) acc = fmaf(hsh[k], W[(size_t)l * Hh + k], acc);
  zws[b * Ll + l] = acc;
  zout[b * Ll + l] = acc;
}

// ---------------- hid0 = tanh(z @ fc_dec_W^T + b) -> dec pair buf0, epoch 0 ----------------
__global__ void k_hid0(const float* __restrict__ z, const float* __restrict__ W,
                       const float* __restrict__ bias, uint2* __restrict__ hp0) {
  int b = blockIdx.x;
  int j = threadIdx.x;  // 512
  __shared__ float zsh[Ll];
  if (threadIdx.x < Ll) zsh[threadIdx.x] = z[b * Ll + threadIdx.x];
  __syncthreads();
  float acc = bias[j];
#pragma unroll 4
  for (int l = 0; l < Ll; l++) acc = fmaf(zsh[l], W[(size_t)j * Ll + l], acc);
  hp0[b * Hh + j] = make_uint2(__float_as_uint(tanhf(acc)), 0u);
}

// ---------------- logits via MFMA bf16 ----------------
template <bool BF16W>
__global__ void __launch_bounds__(256) k_logits_mfma(
    const unsigned short* __restrict__ Abf,  // [2048][512] bf16
    const unsigned short* __restrict__ Wbf,  // [32000][512] bf16 (if BF16W)
    const float* __restrict__ Wf,            // [32000][512] f32 (fallback)
    const float* __restrict__ bias, float* __restrict__ out) {
  const int tid = threadIdx.x;
  const int wid = tid >> 6, lane = tid & 63;
  const int ln = lane & 15, hi = lane >> 4;
  const int n0 = blockIdx.x * 64;
  const int m0 = blockIdx.y * 256 + wid * 64;
  f32x4 acc[4][4];
#pragma unroll
  for (int mi = 0; mi < 4; ++mi)
#pragma unroll
    for (int ni = 0; ni < 4; ++ni) acc[mi][ni] = (f32x4)0.f;

  const unsigned short* ap = Abf + (size_t)(m0 + ln) * Hh + hi * 8;
  const unsigned short* bp16 = Wbf + (size_t)(n0 + ln) * Hh + hi * 8;
  const float* bp32 = Wf + (size_t)(n0 + ln) * Hh + hi * 8;

  for (int kt = 0; kt < 16; ++kt) {
    short8 a[4], b[4];
#pragma unroll
    for (int mi = 0; mi < 4; ++mi)
      a[mi] = *(const short8*)(ap + (size_t)mi * 16 * Hh + kt * 32);
#pragma unroll
    for (int ni = 0; ni < 4; ++ni) {
      if (BF16W) {
        b[ni] = *(const short8*)(bp16 + (size_t)ni * 16 * Hh + kt * 32);
      } else {
        const float* q = bp32 + (size_t)ni * 16 * Hh + kt * 32;
        short8 tv;
#pragma unroll
        for (int e = 0; e < 8; ++e) tv[e] = (short)f2bf(q[e]);
        b[ni] = tv;
      }
    }
#pragma unroll
    for (int mi = 0; mi < 4; ++mi)
#pragma unroll
      for (int ni = 0; ni < 4; ++ni)
        acc[mi][ni] = __builtin_amdgcn_mfma_f32_16x16x32_bf16(a[mi], b[ni], acc[mi][ni], 0, 0, 0);
  }

#pragma unroll
  for (int ni = 0; ni < 4; ++ni) {
    int n = n0 + ni * 16 + ln;
    float bv = bias[n];
#pragma unroll
    for (int mi = 0; mi < 4; ++mi) {
      int mbase = m0 + mi * 16 + hi * 4;
#pragma unroll
      for (int r = 0; r < 4; ++r) {
        int m = mbase + r;
        if (m < 2032) {
          int t = m >> 4, bb = m & 15;
          out[((size_t)(bb * Tt + 1 + t)) * Vv + n] = acc[mi][ni][r] + bv;
        }
      }
    }
  }
}

extern "C" void kernel_launch(void* const* d_in, const int* in_sizes, int n_in,
                              void* d_out, int out_size, void* d_ws, size_t ws_size,
                              hipStream_t stream) {
  const int* x = (const int*)d_in[0];
  const float* enc_emb = (const float*)d_in[1];
  const float* enc_Wih = (const float*)d_in[2];
  const float* enc_bih = (const float*)d_in[3];
  const float* enc_Whh = (const float*)d_in[4];
  const float* enc_bhh = (const float*)d_in[5];
  const float* fc_enc_W = (const float*)d_in[6];
  const float* fc_enc_b = (const float*)d_in[7];
  const float* fc_dec_W = (const float*)d_in[8];
  const float* fc_dec_b = (const float*)d_in[9];
  const float* dec_emb = (const float*)d_in[10];
  const float* dec_Wih = (const float*)d_in[11];
  const float* dec_bih = (const float*)d_in[12];
  const float* dec_Whh = (const float*)d_in[13];
  const float* dec_bhh = (const float*)d_in[14];
  const float* dec_fcW = (const float*)d_in[15];
  const float* dec_fcb = (const float*)d_in[16];
  float* out = (float*)d_out;

  float* ws = (float*)d_ws;
  size_t off = 0;
  float* wihT_e = ws + off; off += 393216;
  float* wihT_d = ws + off; off += 393216;
  float* gx_e = ws + off; off += 3145728;
  float* gx_d = ws + off; off += 3121152;
  uint2* enc_pairs = (uint2*)(ws + off); off += 4 * NPAIR;  // [2][NPAIR] uint2
  uint2* dec_pairs = (uint2*)(ws + off); off += 4 * NPAIR;
  float* zbuf = ws + off; off += 2048;
  unsigned short* hseq_bf = (unsigned short*)(ws + off); off += 524288;
  size_t wbf_elems = (size_t)Vv * Hh;
  bool use_wbf = (off + wbf_elems / 2) * sizeof(float) <= ws_size;
  unsigned short* wbf = (unsigned short*)(ws + off);

  // init: epoch buffers + outputs[:,0,:] = 0
  k_init_pairs<<<(3 * NPAIR + 255) / 256, 256, 0, stream>>>(enc_pairs, dec_pairs + NPAIR - NPAIR);
  k_zero_first<<<(Bb * Vv + 255) / 256, 256, 0, stream>>>(out);

  if (use_wbf)
    k_cvt_bf16<<<(int)((wbf_elems / 4 + 255) / 256), 256, 0, stream>>>(
        dec_fcW, wbf, (int)(wbf_elems / 4));

  dim3 tb(32, 8);
  k_transpose<<<dim3(256 / 32, 1536 / 32), tb, 0, stream>>>(enc_Wih, wihT_e, 1536, 256);
  k_transpose<<<dim3(256 / 32, 1536 / 32), tb, 0, stream>>>(dec_Wih, wihT_d, 1536, 256);

  k_gx<<<dim3(128, 6), 256, 0, stream>>>(x, enc_emb, wihT_e, enc_bih, gx_e);
  k_gx<<<dim3(127, 6), 256, 0, stream>>>(x, dec_emb, wihT_d, dec_bih, gx_d);

  // encoder scan: 128 steps; final h in enc_pairs[0] (epoch 128)
  k_scan<<<NWG, 256, 0, stream>>>(enc_Whh, enc_bhh, gx_e, enc_pairs,
                                  (unsigned short*)nullptr, 128);

  k_z<<<16, 128, 0, stream>>>(enc_pairs, fc_enc_W, fc_enc_b, zbuf,
                              out + (size_t)Bb * Tt * Vv);
  k_hid0<<<16, 512, 0, stream>>>(zbuf, fc_dec_W, fc_dec_b, dec_pairs);

  // decoder scan: 127 steps, record hseq (bf16)
  k_scan<<<NWG, 256, 0, stream>>>(dec_Whh, dec_bhh, gx_d, dec_pairs, hseq_bf, 127);

  // logits
  if (use_wbf)
    k_logits_mfma<true><<<dim3(Vv / 64, 8), 256, 0, stream>>>(hseq_bf, wbf, dec_fcW,
                                                              dec_fcb, out);
  else
    k_logits_mfma<false><<<dim3(Vv / 64, 8), 256, 0, stream>>>(hseq_bf, (unsigned short*)nullptr,
                                                               dec_fcW, dec_fcb, out);
}

// Round 8
// 1919.097 us; speedup vs baseline: 1.1231x; 1.1231x over previous
//
#include <hip/hip_runtime.h>

#define Vv 32000
#define Ee 256
#define Hh 512
#define Ll 128
#define Bb 16
#define Tt 128
#define G3 1536   // 3*H
#define NWG 64    // persistent scan workgroups

typedef __attribute__((ext_vector_type(8))) short short8;
typedef __attribute__((ext_vector_type(4))) float f32x4;

__device__ __forceinline__ float sigmoidf_(float x) { return 1.f / (1.f + __expf(-x)); }

__device__ __forceinline__ unsigned short f2bf(float f) {
  unsigned int u = __float_as_uint(f);
  u = (u + 0x7fffu + ((u >> 16) & 1u)) >> 16;
  return (unsigned short)u;
}

// ---------------- small helpers ----------------
__global__ void k_zero(float* __restrict__ p, int n) {
  int i = blockIdx.x * 256 + threadIdx.x;
  if (i < n) p[i] = 0.f;
}

__global__ void k_zero_first(float* __restrict__ out) {
  int idx = blockIdx.x * 256 + threadIdx.x;
  if (idx < Bb * Vv) {
    int b = idx / Vv, v = idx % Vv;
    out[(size_t)b * Tt * Vv + v] = 0.f;
  }
}

__global__ void k_cvt_bf16(const float* __restrict__ in, unsigned short* __restrict__ out,
                           int n4) {
  int i = blockIdx.x * 256 + threadIdx.x;
  if (i < n4) {
    float4 v = ((const float4*)in)[i];
    ushort4 o;
    o.x = f2bf(v.x); o.y = f2bf(v.y); o.z = f2bf(v.z); o.w = f2bf(v.w);
    ((ushort4*)out)[i] = o;
  }
}

__global__ void k_transpose(const float* __restrict__ in, float* __restrict__ out,
                            int R, int C) {
  __shared__ float tile[32][33];
  int c = blockIdx.x * 32 + threadIdx.x;
  int r0 = blockIdx.y * 32;
  for (int i = threadIdx.y; i < 32; i += 8)
    tile[i][threadIdx.x] = in[(size_t)(r0 + i) * C + c];
  __syncthreads();
  int r = r0 + threadIdx.x;
  int c0 = blockIdx.x * 32;
  for (int i = threadIdx.y; i < 32; i += 8)
    out[(size_t)(c0 + i) * R + r] = tile[threadIdx.x][i];
}

// ---------------- gx body (used standalone for enc, fused for dec) ----------------
__device__ __forceinline__ void gx_body(int e, const int* __restrict__ x,
                                        const float* __restrict__ emb,
                                        const float* __restrict__ WihT,
                                        const float* __restrict__ b_ih,
                                        float* __restrict__ gx) {
  __shared__ float A[16][Ee];
  int mt = e / 6, gy = e % 6;
  int g = gy * 256 + threadIdx.x;
  for (int i = 0; i < 16; i++) {
    int tok = x[i * Tt + mt];
    A[i][threadIdx.x] = emb[(size_t)tok * Ee + threadIdx.x];
  }
  __syncthreads();
  float acc[16];
  float bg = b_ih[g];
#pragma unroll
  for (int i = 0; i < 16; i++) acc[i] = bg;
#pragma unroll 4
  for (int ee = 0; ee < Ee; ee++) {
    float w = WihT[(size_t)ee * G3 + g];
#pragma unroll
    for (int i = 0; i < 16; i++) acc[i] = fmaf(A[i][ee], w, acc[i]);
  }
#pragma unroll
  for (int i = 0; i < 16; i++)
    gx[(size_t)(mt * 16 + i) * G3 + g] = acc[i];
}

__global__ void k_gx(const int* __restrict__ x, const float* __restrict__ emb,
                     const float* __restrict__ WihT, const float* __restrict__ b_ih,
                     float* __restrict__ gx) {
  gx_body(blockIdx.x, x, emb, WihT, b_ih, gx);
}

// ---------------- scan body: r5 structure + 8-way split counters + prog ----------------
template <bool HSEQ>
__device__ __forceinline__ void scan_body(
    const float* __restrict__ Whh, const float* __restrict__ bhh,
    const float* __restrict__ gx, float* __restrict__ hbuf,
    unsigned short* __restrict__ hseq, int nsteps,
    int* __restrict__ cnt,   // 8 lines x 64 ints
    int* __restrict__ prog) {
  __shared__ float h_lds[Bb * Hh];            // 32 KB
  __shared__ float scratch[4][8][3][Bb];      // 6 KB
  const int tid = threadIdx.x;
  const int wg = blockIdx.x;
  const int jloc = tid & 7;
  const int ks = tid >> 3;    // 0..31
  const int j = wg * 8 + jloc;
  const int k0 = ks * 16;

  float wr[16], wz[16], wn[16];
  {
    const float4* R = (const float4*)(Whh + (size_t)j * Hh + k0);
    const float4* Z = (const float4*)(Whh + (size_t)(Hh + j) * Hh + k0);
    const float4* N = (const float4*)(Whh + (size_t)(2 * Hh + j) * Hh + k0);
#pragma unroll
    for (int q = 0; q < 4; ++q) {
      float4 a = R[q]; wr[4*q] = a.x; wr[4*q+1] = a.y; wr[4*q+2] = a.z; wr[4*q+3] = a.w;
      float4 b = Z[q]; wz[4*q] = b.x; wz[4*q+1] = b.y; wz[4*q+2] = b.z; wz[4*q+3] = b.w;
      float4 c = N[q]; wn[4*q] = c.x; wn[4*q+1] = c.y; wn[4*q+2] = c.z; wn[4*q+3] = c.w;
    }
  }
  float bhr = 0.f, bhz = 0.f, bhn = 0.f;
  if (tid < 128) { bhr = bhh[j]; bhz = bhh[Hh + j]; bhn = bhh[2 * Hh + j]; }

  float xr = 0.f, xz = 0.f, xn = 0.f;
  if (tid < 128) {
    const float* gp = gx + (size_t)ks * G3 + j;
    xr = gp[0]; xz = gp[Hh]; xn = gp[2 * Hh];
  }

  for (int t = 0; t < nsteps; ++t) {
    // stage h(t) -> LDS (sc1 wide loads; fresh at LLC)
    {
      const f32x4* hsrc = (const f32x4*)(hbuf + (size_t)(t & 1) * (Bb * Hh));
      f32x4 hv[8];
#pragma unroll
      for (int i = 0; i < 8; ++i) {
        const f32x4* p = hsrc + tid + 256 * i;
        asm volatile("global_load_dwordx4 %0, %1, off sc1" : "=v"(hv[i]) : "v"(p));
      }
      asm volatile("s_waitcnt vmcnt(0)" ::: "memory");
      f32x4* hl = (f32x4*)h_lds;
#pragma unroll
      for (int i = 0; i < 8; ++i) hl[tid + 256 * i] = hv[i];
    }
    __syncthreads();

    float accR[Bb], accZ[Bb], accN[Bb];
#pragma unroll
    for (int b = 0; b < Bb; ++b) { accR[b] = 0.f; accZ[b] = 0.f; accN[b] = 0.f; }
#pragma unroll
    for (int b = 0; b < Bb; ++b) {
      const float4* hp = (const float4*)(h_lds + b * Hh + k0);
#pragma unroll
      for (int q = 0; q < 4; ++q) {
        float4 hv = hp[q];
        accR[b] = fmaf(wr[4*q+0], hv.x, accR[b]);
        accR[b] = fmaf(wr[4*q+1], hv.y, accR[b]);
        accR[b] = fmaf(wr[4*q+2], hv.z, accR[b]);
        accR[b] = fmaf(wr[4*q+3], hv.w, accR[b]);
        accZ[b] = fmaf(wz[4*q+0], hv.x, accZ[b]);
        accZ[b] = fmaf(wz[4*q+1], hv.y, accZ[b]);
        accZ[b] = fmaf(wz[4*q+2], hv.z, accZ[b]);
        accZ[b] = fmaf(wz[4*q+3], hv.w, accZ[b]);
        accN[b] = fmaf(wn[4*q+0], hv.x, accN[b]);
        accN[b] = fmaf(wn[4*q+1], hv.y, accN[b]);
        accN[b] = fmaf(wn[4*q+2], hv.z, accN[b]);
        accN[b] = fmaf(wn[4*q+3], hv.w, accN[b]);
      }
    }
#pragma unroll
    for (int b = 0; b < Bb; ++b) {
      accR[b] += __shfl_xor(accR[b], 8, 64);
      accR[b] += __shfl_xor(accR[b], 16, 64);
      accR[b] += __shfl_xor(accR[b], 32, 64);
      accZ[b] += __shfl_xor(accZ[b], 8, 64);
      accZ[b] += __shfl_xor(accZ[b], 16, 64);
      accZ[b] += __shfl_xor(accZ[b], 32, 64);
      accN[b] += __shfl_xor(accN[b], 8, 64);
      accN[b] += __shfl_xor(accN[b], 16, 64);
      accN[b] += __shfl_xor(accN[b], 32, 64);
    }
    if ((ks & 7) == 0) {
      const int wv = tid >> 6;
#pragma unroll
      for (int b = 0; b < Bb; ++b) {
        scratch[wv][jloc][0][b] = accR[b];
        scratch[wv][jloc][1][b] = accZ[b];
        scratch[wv][jloc][2][b] = accN[b];
      }
    }
    __syncthreads();

    float* hdst = hbuf + (size_t)((t + 1) & 1) * (Bb * Hh);
    if (tid < 128) {
      const int b = ks;
      float ar = scratch[0][jloc][0][b] + scratch[1][jloc][0][b] +
                 scratch[2][jloc][0][b] + scratch[3][jloc][0][b] + bhr;
      float az = scratch[0][jloc][1][b] + scratch[1][jloc][1][b] +
                 scratch[2][jloc][1][b] + scratch[3][jloc][1][b] + bhz;
      float an = scratch[0][jloc][2][b] + scratch[1][jloc][2][b] +
                 scratch[2][jloc][2][b] + scratch[3][jloc][2][b] + bhn;
      float r = sigmoidf_(xr + ar);
      float u = sigmoidf_(xz + az);
      float n = tanhf(xn + r * an);
      float hold = h_lds[b * Hh + j];
      float hnew = (1.f - u) * n + u * hold;
      __hip_atomic_store((int*)hdst + b * Hh + j, __float_as_int(hnew),
                         __ATOMIC_RELAXED, __HIP_MEMORY_SCOPE_AGENT);
      if (HSEQ) {
        unsigned short* hp = hseq + ((size_t)t * Bb + b) * Hh + j;
        int hv = (int)f2bf(hnew);
        asm volatile("global_store_short %0, %1, off sc1" : : "v"(hp), "v"(hv) : "memory");
      }
    }

    // ---- arrive: drain, then split-counter add (8 WGs per line) ----
    asm volatile("s_waitcnt vmcnt(0)" ::: "memory");
    __syncthreads();
    if (tid == 0)
      __hip_atomic_fetch_add(&cnt[64 * (wg & 7)], 1, __ATOMIC_RELAXED,
                             __HIP_MEMORY_SCOPE_AGENT);
    // prefetch next step's gx while waiting
    if (tid < 128 && t + 1 < nsteps) {
      const float* gp = gx + (size_t)((t + 1) * Bb + ks) * G3 + j;
      xr = gp[0]; xz = gp[Hh]; xn = gp[2 * Hh];
    }
    // ---- wait: wave0 polls all 8 lines in parallel (bounded spin) ----
    if (t < nsteps - 1 || wg == 0) {
      if (tid < 64) {
        const int tgt = (t + 1) * 8;
        int* myc = cnt + 64 * (tid & 7);
        for (int it = 0; it < 100000; ++it) {
          int v;
          asm volatile("global_load_dword %0, %1, off sc1\n\ts_waitcnt vmcnt(0)"
                       : "=v"(v) : "v"(myc) : "memory");
          if (__all(v >= tgt)) break;
        }
        if (wg == 0 && tid == 0) {
          int pv = t + 1;
          asm volatile("global_store_dword %0, %1, off sc1"
                       : : "v"(prog), "v"(pv) : "memory");
        }
      }
      __syncthreads();
    }
  }
}

// ---------------- logits body (fused into decoder launch) ----------------
template <bool BF16W>
__device__ __forceinline__ void logits_body(
    int l, const unsigned short* __restrict__ Abf,
    const unsigned short* __restrict__ Wbf, const float* __restrict__ Wf,
    const float* __restrict__ bias, float* __restrict__ out,
    int* __restrict__ prog) {
  const int tid = threadIdx.x;
  const int m_blk = l & 7, n_blk = l >> 3;   // m-interleaved: early t first
  const int n0 = n_blk * 64;
  const int wid = tid >> 6, lane = tid & 63;
  const int ln = lane & 15, hi = lane >> 4;
  const int m0 = m_blk * 256 + wid * 64;
  const int t_need = min(m_blk * 16 + 16, 127);

  __shared__ int s_ready;
  if (tid == 0) {
    int p = 0;
    for (int it = 0; it < 200000; ++it) {
      asm volatile("global_load_dword %0, %1, off sc1\n\ts_waitcnt vmcnt(0)"
                   : "=v"(p) : "v"(prog) : "memory");
      if (p >= t_need) break;
      for (int s = 0; s <= (l & 7); ++s) __builtin_amdgcn_s_sleep(64);
    }
    s_ready = p;
  }
  __syncthreads();

  f32x4 acc[4][4];
#pragma unroll
  for (int mi = 0; mi < 4; ++mi)
#pragma unroll
    for (int ni = 0; ni < 4; ++ni) acc[mi][ni] = (f32x4)0.f;

  const unsigned short* ap = Abf + (size_t)(m0 + ln) * Hh + hi * 8;
  const unsigned short* bp16 = Wbf + (size_t)(n0 + ln) * Hh + hi * 8;
  const float* bp32 = Wf + (size_t)(n0 + ln) * Hh + hi * 8;

  for (int kt = 0; kt < 16; ++kt) {
    short8 a[4], b[4];
#pragma unroll
    for (int mi = 0; mi < 4; ++mi) {
      const short8* pa = (const short8*)(ap + (size_t)mi * 16 * Hh + kt * 32);
      asm volatile("global_load_dwordx4 %0, %1, off sc1" : "=v"(a[mi]) : "v"(pa));
    }
#pragma unroll
    for (int ni = 0; ni < 4; ++ni) {
      if (BF16W) {
        b[ni] = *(const short8*)(bp16 + (size_t)ni * 16 * Hh + kt * 32);
      } else {
        const float* q = bp32 + (size_t)ni * 16 * Hh + kt * 32;
        short8 tv;
#pragma unroll
        for (int e = 0; e < 8; ++e) tv[e] = (short)f2bf(q[e]);
        b[ni] = tv;
      }
    }
    asm volatile("s_waitcnt vmcnt(0)" ::: "memory");
#pragma unroll
    for (int mi = 0; mi < 4; ++mi)
#pragma unroll
      for (int ni = 0; ni < 4; ++ni)
        acc[mi][ni] = __builtin_amdgcn_mfma_f32_16x16x32_bf16(a[mi], b[ni], acc[mi][ni], 0, 0, 0);
  }

#pragma unroll
  for (int ni = 0; ni < 4; ++ni) {
    int n = n0 + ni * 16 + ln;
    float bv = bias[n];
#pragma unroll
    for (int mi = 0; mi < 4; ++mi) {
      int mbase = m0 + mi * 16 + hi * 4;
#pragma unroll
      for (int r = 0; r < 4; ++r) {
        int m = mbase + r;
        if (m < 2032) {
          int t = m >> 4, bb = m & 15;
          out[((size_t)(bb * Tt + 1 + t)) * Vv + n] = acc[mi][ni][r] + bv;
        }
      }
    }
  }
}

// ---------------- fused kernels ----------------
__global__ void __launch_bounds__(256) k_enc_fused(
    const float* __restrict__ Whh, const float* __restrict__ bhh,
    const float* __restrict__ gx_e, float* __restrict__ hbuf,
    int* __restrict__ cnt, int* __restrict__ prog,
    const int* __restrict__ x, const float* __restrict__ dec_emb,
    const float* __restrict__ wihT_d, const float* __restrict__ dec_bih,
    float* __restrict__ gx_d) {
  if (blockIdx.x < NWG)
    scan_body<false>(Whh, bhh, gx_e, hbuf, (unsigned short*)nullptr, Tt, cnt, prog);
  else
    gx_body(blockIdx.x - NWG, x, dec_emb, wihT_d, dec_bih, gx_d);
}

template <bool BF16W>
__global__ void __launch_bounds__(256) k_dec_fused(
    const float* __restrict__ Whh, const float* __restrict__ bhh,
    const float* __restrict__ gx_d, float* __restrict__ hbuf,
    unsigned short* __restrict__ hseq, int* __restrict__ cnt, int* __restrict__ prog,
    const unsigned short* __restrict__ Wbf, const float* __restrict__ Wf,
    const float* __restrict__ bias, float* __restrict__ out) {
  if (blockIdx.x < NWG)
    scan_body<true>(Whh, bhh, gx_d, hbuf, hseq, Tt - 1, cnt, prog);
  else
    logits_body<BF16W>(blockIdx.x - NWG, hseq, Wbf, Wf, bias, out, prog);
}

// ---------------- z and hid0 ----------------
__global__ void k_z(const float* __restrict__ h, const float* __restrict__ W,
                    const float* __restrict__ bias, float* __restrict__ zws,
                    float* __restrict__ zout) {
  int b = blockIdx.x;
  int l = threadIdx.x;  // 128
  __shared__ float hsh[Hh];
  for (int i = threadIdx.x; i < Hh; i += 128) hsh[i] = h[b * Hh + i];
  __syncthreads();
  float acc = bias[l];
#pragma unroll 4
  for (int k = 0; k < Hh; k++) acc = fmaf(hsh[k], W[(size_t)l * Hh + k], acc);
  zws[b * Ll + l] = acc;
  zout[b * Ll + l] = acc;
}

__global__ void k_hid0(const float* __restrict__ z, const float* __restrict__ W,
                       const float* __restrict__ bias, float* __restrict__ h0) {
  int b = blockIdx.x;
  int j = threadIdx.x;  // 512
  __shared__ float zsh[Ll];
  if (threadIdx.x < Ll) zsh[threadIdx.x] = z[b * Ll + threadIdx.x];
  __syncthreads();
  float acc = bias[j];
#pragma unroll 4
  for (int l = 0; l < Ll; l++) acc = fmaf(zsh[l], W[(size_t)j * Ll + l], acc);
  h0[b * Hh + j] = tanhf(acc);
}

extern "C" void kernel_launch(void* const* d_in, const int* in_sizes, int n_in,
                              void* d_out, int out_size, void* d_ws, size_t ws_size,
                              hipStream_t stream) {
  const int* x = (const int*)d_in[0];
  const float* enc_emb = (const float*)d_in[1];
  const float* enc_Wih = (const float*)d_in[2];
  const float* enc_bih = (const float*)d_in[3];
  const float* enc_Whh = (const float*)d_in[4];
  const float* enc_bhh = (const float*)d_in[5];
  const float* fc_enc_W = (const float*)d_in[6];
  const float* fc_enc_b = (const float*)d_in[7];
  const float* fc_dec_W = (const float*)d_in[8];
  const float* fc_dec_b = (const float*)d_in[9];
  const float* dec_emb = (const float*)d_in[10];
  const float* dec_Wih = (const float*)d_in[11];
  const float* dec_bih = (const float*)d_in[12];
  const float* dec_Whh = (const float*)d_in[13];
  const float* dec_bhh = (const float*)d_in[14];
  const float* dec_fcW = (const float*)d_in[15];
  const float* dec_fcb = (const float*)d_in[16];
  float* out = (float*)d_out;

  float* ws = (float*)d_ws;
  size_t off = 0;
  float* wihT_e = ws + off; off += 393216;
  float* wihT_d = ws + off; off += 393216;
  float* gx_e = ws + off; off += 3145728;
  float* gx_d = ws + off; off += 3121152;
  float* hbuf = ws + off; off += 16384;
  float* zbuf = ws + off; off += 2048;
  // ctrl: cnt_e[8*64] cnt_d[8*64] prog_e[64] prog_d[64]
  int* ctrl = (int*)(ws + off); off += 1152;
  int* cnt_e = ctrl;
  int* cnt_d = ctrl + 512;
  int* prog_e = ctrl + 1024;
  int* prog_d = ctrl + 1088;
  unsigned short* hseq_bf = (unsigned short*)(ws + off); off += 524288;
  size_t wbf_elems = (size_t)Vv * Hh;
  bool use_wbf = (off + wbf_elems / 2) * sizeof(float) <= ws_size;
  unsigned short* wbf = (unsigned short*)(ws + off);

  // init
  hipMemsetAsync(ctrl, 0, 1152 * sizeof(int), stream);
  k_zero<<<(Bb * Hh + 255) / 256, 256, 0, stream>>>(hbuf, Bb * Hh);
  k_zero_first<<<(Bb * Vv + 255) / 256, 256, 0, stream>>>(out);

  if (use_wbf)
    k_cvt_bf16<<<(int)((wbf_elems / 4 + 255) / 256), 256, 0, stream>>>(
        dec_fcW, wbf, (int)(wbf_elems / 4));

  dim3 tb(32, 8);
  k_transpose<<<dim3(256 / 32, 1536 / 32), tb, 0, stream>>>(enc_Wih, wihT_e, 1536, 256);
  k_transpose<<<dim3(256 / 32, 1536 / 32), tb, 0, stream>>>(dec_Wih, wihT_d, 1536, 256);

  // gx_e (decoder gx is fused into the encoder-scan launch below)
  k_gx<<<128 * 6, 256, 0, stream>>>(x, enc_emb, wihT_e, enc_bih, gx_e);

  // encoder scan (64 WGs) + gx_d (127*6 = 762 extra WGs)
  k_enc_fused<<<NWG + 762, 256, 0, stream>>>(enc_Whh, enc_bhh, gx_e, hbuf,
                                             cnt_e, prog_e,
                                             x, dec_emb, wihT_d, dec_bih, gx_d);

  k_z<<<16, 128, 0, stream>>>(hbuf, fc_enc_W, fc_enc_b, zbuf, out + (size_t)Bb * Tt * Vv);
  k_hid0<<<16, 512, 0, stream>>>(zbuf, fc_dec_W, fc_dec_b, hbuf);

  // decoder scan (64 WGs) + logits (500*8 = 4000 extra WGs, gated on prog)
  if (use_wbf)
    k_dec_fused<true><<<NWG + 4000, 256, 0, stream>>>(dec_Whh, dec_bhh, gx_d, hbuf,
                                                      hseq_bf, cnt_d, prog_d,
                                                      wbf, dec_fcW, dec_fcb, out);
  else
    k_dec_fused<false><<<NWG + 4000, 256, 0, stream>>>(dec_Whh, dec_bhh, gx_d, hbuf,
                                                       hseq_bf, cnt_d, prog_d,
                                                       (unsigned short*)nullptr, dec_fcW,
                                                       dec_fcb, out);
}

// Round 9
// 1739.201 us; speedup vs baseline: 1.2393x; 1.1034x over previous
//
#include <hip/hip_runtime.h>

#define Vv 32000
#define Ee 256
#define Hh 512
#define Ll 128
#define Bb 16
#define Tt 128
#define G3 1536   // 3*H
#define NWG 64    // persistent scan workgroups

typedef __attribute__((ext_vector_type(8))) short short8;
typedef __attribute__((ext_vector_type(4))) float f32x4;

__device__ __forceinline__ float sigmoidf_(float x) { return 1.f / (1.f + __expf(-x)); }

__device__ __forceinline__ unsigned short f2bf(float f) {
  unsigned int u = __float_as_uint(f);
  u = (u + 0x7fffu + ((u >> 16) & 1u)) >> 16;
  return (unsigned short)u;
}

// ---------------- small helpers ----------------
__global__ void k_zero(float* __restrict__ p, int n) {
  int i = blockIdx.x * 256 + threadIdx.x;
  if (i < n) p[i] = 0.f;
}

__global__ void k_zero_first(float* __restrict__ out) {
  int idx = blockIdx.x * 256 + threadIdx.x;
  if (idx < Bb * Vv) {
    int b = idx / Vv, v = idx % Vv;
    out[(size_t)b * Tt * Vv + v] = 0.f;
  }
}

__global__ void k_cvt_bf16(const float* __restrict__ in, unsigned short* __restrict__ out,
                           int n4) {
  int i = blockIdx.x * 256 + threadIdx.x;
  if (i < n4) {
    float4 v = ((const float4*)in)[i];
    ushort4 o;
    o.x = f2bf(v.x); o.y = f2bf(v.y); o.z = f2bf(v.z); o.w = f2bf(v.w);
    ((ushort4*)out)[i] = o;
  }
}

__global__ void k_transpose(const float* __restrict__ in, float* __restrict__ out,
                            int R, int C) {
  __shared__ float tile[32][33];
  int c = blockIdx.x * 32 + threadIdx.x;
  int r0 = blockIdx.y * 32;
  for (int i = threadIdx.y; i < 32; i += 8)
    tile[i][threadIdx.x] = in[(size_t)(r0 + i) * C + c];
  __syncthreads();
  int r = r0 + threadIdx.x;
  int c0 = blockIdx.x * 32;
  for (int i = threadIdx.y; i < 32; i += 8)
    out[(size_t)(c0 + i) * R + r] = tile[threadIdx.x][i];
}

// ---------------- gx body ----------------
__device__ __forceinline__ void gx_body(int e, const int* __restrict__ x,
                                        const float* __restrict__ emb,
                                        const float* __restrict__ WihT,
                                        const float* __restrict__ b_ih,
                                        float* __restrict__ gx) {
  __shared__ float A[16][Ee];
  int mt = e / 6, gy = e % 6;
  int g = gy * 256 + threadIdx.x;
  for (int i = 0; i < 16; i++) {
    int tok = x[i * Tt + mt];
    A[i][threadIdx.x] = emb[(size_t)tok * Ee + threadIdx.x];
  }
  __syncthreads();
  float acc[16];
  float bg = b_ih[g];
#pragma unroll
  for (int i = 0; i < 16; i++) acc[i] = bg;
#pragma unroll 4
  for (int ee = 0; ee < Ee; ee++) {
    float w = WihT[(size_t)ee * G3 + g];
#pragma unroll
    for (int i = 0; i < 16; i++) acc[i] = fmaf(A[i][ee], w, acc[i]);
  }
#pragma unroll
  for (int i = 0; i < 16; i++)
    gx[(size_t)(mt * 16 + i) * G3 + g] = acc[i];
}

__global__ void k_gx(const int* __restrict__ x, const float* __restrict__ emb,
                     const float* __restrict__ WihT, const float* __restrict__ b_ih,
                     float* __restrict__ gx) {
  gx_body(blockIdx.x, x, emb, WihT, b_ih, gx);
}

// ---------------- scan body: wave-self-contained inner loop ----------------
// lane = ks(4b)<<2 | jl(2b); wave = bh<<1 | jh.
// Lane owns column j = wg*8 + jh*4 + jl, k-segment [ks*32, ks*32+32), batches bh*8..bh*8+7.
// k-reduce = 4 shfl_xor within wave. Gate lanes (ks<8) each finish one (j, b=bh*8+ks) pair.
template <bool HSEQ>
__device__ __forceinline__ void scan_body(
    const float* __restrict__ Whh, const float* __restrict__ bhh,
    const float* __restrict__ gx, float* __restrict__ hbuf,
    unsigned short* __restrict__ hseq, int nsteps,
    int* __restrict__ cnt) {   // 8 lines x 64 ints
  __shared__ float h_lds[Bb * Hh];            // 32 KB
  const int tid = threadIdx.x;
  const int wg = blockIdx.x;
  const int lane = tid & 63;
  const int wave = tid >> 6;
  const int jl = lane & 3;
  const int ks = lane >> 2;      // 0..15
  const int jh = wave & 1;
  const int bh = wave >> 1;      // 0..1
  const int j = wg * 8 + jh * 4 + jl;
  const int k0 = ks * 32;
  const int bsel = bh * 8 + ks;  // gate-lane batch (valid when ks<8)
  const bool gate = (ks < 8);

  // weights: 3 gates x 32 k in f32 regs (96 VGPRs)
  float wr[32], wz[32], wn[32];
  {
    const float4* R = (const float4*)(Whh + (size_t)j * Hh + k0);
    const float4* Z = (const float4*)(Whh + (size_t)(Hh + j) * Hh + k0);
    const float4* N = (const float4*)(Whh + (size_t)(2 * Hh + j) * Hh + k0);
#pragma unroll
    for (int q = 0; q < 8; ++q) {
      float4 a = R[q]; wr[4*q] = a.x; wr[4*q+1] = a.y; wr[4*q+2] = a.z; wr[4*q+3] = a.w;
      float4 b = Z[q]; wz[4*q] = b.x; wz[4*q+1] = b.y; wz[4*q+2] = b.z; wz[4*q+3] = b.w;
      float4 c = N[q]; wn[4*q] = c.x; wn[4*q+1] = c.y; wn[4*q+2] = c.z; wn[4*q+3] = c.w;
    }
  }
  const float bhr = bhh[j], bhz = bhh[Hh + j], bhn = bhh[2 * Hh + j];

  // gx for step 0 (gate lanes)
  float xr = 0.f, xz = 0.f, xn = 0.f;
  if (gate) {
    const float* gp = gx + (size_t)bsel * G3 + j;
    xr = gp[0]; xz = gp[Hh]; xn = gp[2 * Hh];
  }

  for (int t = 0; t < nsteps; ++t) {
    // ---- stage h(t) -> LDS (sc1 wide loads: LLC-fresh) ----
    {
      const f32x4* hsrc = (const f32x4*)(hbuf + (size_t)(t & 1) * (Bb * Hh));
      f32x4 hv[8];
#pragma unroll
      for (int i = 0; i < 8; ++i) {
        const f32x4* p = hsrc + tid + 256 * i;
        asm volatile("global_load_dwordx4 %0, %1, off sc1" : "=v"(hv[i]) : "v"(p));
      }
      asm volatile("s_waitcnt vmcnt(0)" ::: "memory");
      f32x4* hl = (f32x4*)h_lds;
#pragma unroll
      for (int i = 0; i < 8; ++i) hl[tid + 256 * i] = hv[i];
    }
    __syncthreads();

    // ---- per-lane partial dots (reg weights x LDS h) ----
    float accR[8], accZ[8], accN[8];
#pragma unroll
    for (int b8 = 0; b8 < 8; ++b8) { accR[b8] = 0.f; accZ[b8] = 0.f; accN[b8] = 0.f; }
#pragma unroll
    for (int b8 = 0; b8 < 8; ++b8) {
      const float4* hp = (const float4*)(h_lds + (bh * 8 + b8) * Hh + k0);
#pragma unroll
      for (int q = 0; q < 8; ++q) {
        float4 hv = hp[q];
        accR[b8] = fmaf(wr[4*q+0], hv.x, accR[b8]);
        accR[b8] = fmaf(wr[4*q+1], hv.y, accR[b8]);
        accR[b8] = fmaf(wr[4*q+2], hv.z, accR[b8]);
        accR[b8] = fmaf(wr[4*q+3], hv.w, accR[b8]);
        accZ[b8] = fmaf(wz[4*q+0], hv.x, accZ[b8]);
        accZ[b8] = fmaf(wz[4*q+1], hv.y, accZ[b8]);
        accZ[b8] = fmaf(wz[4*q+2], hv.z, accZ[b8]);
        accZ[b8] = fmaf(wz[4*q+3], hv.w, accZ[b8]);
        accN[b8] = fmaf(wn[4*q+0], hv.x, accN[b8]);
        accN[b8] = fmaf(wn[4*q+1], hv.y, accN[b8]);
        accN[b8] = fmaf(wn[4*q+2], hv.z, accN[b8]);
        accN[b8] = fmaf(wn[4*q+3], hv.w, accN[b8]);
      }
    }
    // ---- reduce over ks (lane bits 2..5), fully within wave ----
#pragma unroll
    for (int b8 = 0; b8 < 8; ++b8) {
      accR[b8] += __shfl_xor(accR[b8], 4, 64);
      accR[b8] += __shfl_xor(accR[b8], 8, 64);
      accR[b8] += __shfl_xor(accR[b8], 16, 64);
      accR[b8] += __shfl_xor(accR[b8], 32, 64);
      accZ[b8] += __shfl_xor(accZ[b8], 4, 64);
      accZ[b8] += __shfl_xor(accZ[b8], 8, 64);
      accZ[b8] += __shfl_xor(accZ[b8], 16, 64);
      accZ[b8] += __shfl_xor(accZ[b8], 32, 64);
      accN[b8] += __shfl_xor(accN[b8], 4, 64);
      accN[b8] += __shfl_xor(accN[b8], 8, 64);
      accN[b8] += __shfl_xor(accN[b8], 16, 64);
      accN[b8] += __shfl_xor(accN[b8], 32, 64);
    }
    // ---- static-index batch select: gate lane ks handles b8 = ks ----
    float ar = 0.f, az = 0.f, an_ = 0.f;
#pragma unroll
    for (int b8 = 0; b8 < 8; ++b8)
      if (ks == b8) { ar = accR[b8]; az = accZ[b8]; an_ = accN[b8]; }

    float* hdst = hbuf + (size_t)((t + 1) & 1) * (Bb * Hh);
    if (gate) {
      float r = sigmoidf_(xr + ar + bhr);
      float u = sigmoidf_(xz + az + bhz);
      float n = tanhf(xn + r * (an_ + bhn));
      float hold = h_lds[bsel * Hh + j];
      float hnew = (1.f - u) * n + u * hold;
      __hip_atomic_store((int*)hdst + bsel * Hh + j, __float_as_int(hnew),
                         __ATOMIC_RELAXED, __HIP_MEMORY_SCOPE_AGENT);
      if (HSEQ) hseq[((size_t)t * Bb + bsel) * Hh + j] = f2bf(hnew);
    }

    // ---- barrier: drain, split-counter arrive, wave0 bounded poll ----
    if (t < nsteps - 1) {
      asm volatile("s_waitcnt vmcnt(0)" ::: "memory");
      __syncthreads();
      if (tid == 0)
        __hip_atomic_fetch_add(&cnt[64 * (wg & 7)], 1, __ATOMIC_RELAXED,
                               __HIP_MEMORY_SCOPE_AGENT);
      if (gate) {  // prefetch next step's gx under the wait
        const float* gp = gx + (size_t)((t + 1) * Bb + bsel) * G3 + j;
        xr = gp[0]; xz = gp[Hh]; xn = gp[2 * Hh];
      }
      if (tid < 64) {
        const int tgt = (t + 1) * 8;
        int* myc = cnt + 64 * (tid & 7);
        for (int it = 0; it < 100000; ++it) {
          int v;
          asm volatile("global_load_dword %0, %1, off sc1\n\ts_waitcnt vmcnt(0)"
                       : "=v"(v) : "v"(myc) : "memory");
          if (__all(v >= tgt)) break;
        }
      }
      __syncthreads();
    }
  }
}

// ---------------- fused enc kernel: scan + decoder gx ----------------
__global__ void __launch_bounds__(256) k_enc_fused(
    const float* __restrict__ Whh, const float* __restrict__ bhh,
    const float* __restrict__ gx_e, float* __restrict__ hbuf,
    int* __restrict__ cnt,
    const int* __restrict__ x, const float* __restrict__ dec_emb,
    const float* __restrict__ wihT_d, const float* __restrict__ dec_bih,
    float* __restrict__ gx_d) {
  if (blockIdx.x < NWG)
    scan_body<false>(Whh, bhh, gx_e, hbuf, (unsigned short*)nullptr, Tt, cnt);
  else
    gx_body(blockIdx.x - NWG, x, dec_emb, wihT_d, dec_bih, gx_d);
}

// ---------------- standalone decoder scan ----------------
__global__ void __launch_bounds__(256) k_dec_scan(
    const float* __restrict__ Whh, const float* __restrict__ bhh,
    const float* __restrict__ gx_d, float* __restrict__ hbuf,
    unsigned short* __restrict__ hseq, int* __restrict__ cnt) {
  scan_body<true>(Whh, bhh, gx_d, hbuf, hseq, Tt - 1, cnt);
}

// ---------------- z and hid0 ----------------
__global__ void k_z(const float* __restrict__ h, const float* __restrict__ W,
                    const float* __restrict__ bias, float* __restrict__ zws,
                    float* __restrict__ zout) {
  int b = blockIdx.x;
  int l = threadIdx.x;  // 128
  __shared__ float hsh[Hh];
  for (int i = threadIdx.x; i < Hh; i += 128) hsh[i] = h[b * Hh + i];
  __syncthreads();
  float acc = bias[l];
#pragma unroll 4
  for (int k = 0; k < Hh; k++) acc = fmaf(hsh[k], W[(size_t)l * Hh + k], acc);
  zws[b * Ll + l] = acc;
  zout[b * Ll + l] = acc;
}

__global__ void k_hid0(const float* __restrict__ z, const float* __restrict__ W,
                       const float* __restrict__ bias, float* __restrict__ h0) {
  int b = blockIdx.x;
  int j = threadIdx.x;  // 512
  __shared__ float zsh[Ll];
  if (threadIdx.x < Ll) zsh[threadIdx.x] = z[b * Ll + threadIdx.x];
  __syncthreads();
  float acc = bias[j];
#pragma unroll 4
  for (int l = 0; l < Ll; l++) acc = fmaf(zsh[l], W[(size_t)j * Ll + l], acc);
  h0[b * Hh + j] = tanhf(acc);
}

// ---------------- logits via MFMA bf16 (standalone) ----------------
template <bool BF16W>
__global__ void __launch_bounds__(256) k_logits_mfma(
    const unsigned short* __restrict__ Abf,  // [2048][512] bf16
    const unsigned short* __restrict__ Wbf,  // [32000][512] bf16 (if BF16W)
    const float* __restrict__ Wf,            // [32000][512] f32 (fallback)
    const float* __restrict__ bias, float* __restrict__ out) {
  const int tid = threadIdx.x;
  const int wid = tid >> 6, lane = tid & 63;
  const int ln = lane & 15, hi = lane >> 4;
  const int n0 = blockIdx.x * 64;
  const int m0 = blockIdx.y * 256 + wid * 64;
  f32x4 acc[4][4];
#pragma unroll
  for (int mi = 0; mi < 4; ++mi)
#pragma unroll
    for (int ni = 0; ni < 4; ++ni) acc[mi][ni] = (f32x4)0.f;

  const unsigned short* ap = Abf + (size_t)(m0 + ln) * Hh + hi * 8;
  const unsigned short* bp16 = Wbf + (size_t)(n0 + ln) * Hh + hi * 8;
  const float* bp32 = Wf + (size_t)(n0 + ln) * Hh + hi * 8;

  for (int kt = 0; kt < 16; ++kt) {
    short8 a[4], b[4];
#pragma unroll
    for (int mi = 0; mi < 4; ++mi)
      a[mi] = *(const short8*)(ap + (size_t)mi * 16 * Hh + kt * 32);
#pragma unroll
    for (int ni = 0; ni < 4; ++ni) {
      if (BF16W) {
        b[ni] = *(const short8*)(bp16 + (size_t)ni * 16 * Hh + kt * 32);
      } else {
        const float* q = bp32 + (size_t)ni * 16 * Hh + kt * 32;
        short8 tv;
#pragma unroll
        for (int e = 0; e < 8; ++e) tv[e] = (short)f2bf(q[e]);
        b[ni] = tv;
      }
    }
#pragma unroll
    for (int mi = 0; mi < 4; ++mi)
#pragma unroll
      for (int ni = 0; ni < 4; ++ni)
        acc[mi][ni] = __builtin_amdgcn_mfma_f32_16x16x32_bf16(a[mi], b[ni], acc[mi][ni], 0, 0, 0);
  }

#pragma unroll
  for (int ni = 0; ni < 4; ++ni) {
    int n = n0 + ni * 16 + ln;
    float bv = bias[n];
#pragma unroll
    for (int mi = 0; mi < 4; ++mi) {
      int mbase = m0 + mi * 16 + hi * 4;
#pragma unroll
      for (int r = 0; r < 4; ++r) {
        int m = mbase + r;
        if (m < 2032) {
          int t = m >> 4, bb = m & 15;
          out[((size_t)(bb * Tt + 1 + t)) * Vv + n] = acc[mi][ni][r] + bv;
        }
      }
    }
  }
}

extern "C" void kernel_launch(void* const* d_in, const int* in_sizes, int n_in,
                              void* d_out, int out_size, void* d_ws, size_t ws_size,
                              hipStream_t stream) {
  const int* x = (const int*)d_in[0];
  const float* enc_emb = (const float*)d_in[1];
  const float* enc_Wih = (const float*)d_in[2];
  const float* enc_bih = (const float*)d_in[3];
  const float* enc_Whh = (const float*)d_in[4];
  const float* enc_bhh = (const float*)d_in[5];
  const float* fc_enc_W = (const float*)d_in[6];
  const float* fc_enc_b = (const float*)d_in[7];
  const float* fc_dec_W = (const float*)d_in[8];
  const float* fc_dec_b = (const float*)d_in[9];
  const float* dec_emb = (const float*)d_in[10];
  const float* dec_Wih = (const float*)d_in[11];
  const float* dec_bih = (const float*)d_in[12];
  const float* dec_Whh = (const float*)d_in[13];
  const float* dec_bhh = (const float*)d_in[14];
  const float* dec_fcW = (const float*)d_in[15];
  const float* dec_fcb = (const float*)d_in[16];
  float* out = (float*)d_out;

  float* ws = (float*)d_ws;
  size_t off = 0;
  float* wihT_e = ws + off; off += 393216;
  float* wihT_d = ws + off; off += 393216;
  float* gx_e = ws + off; off += 3145728;
  float* gx_d = ws + off; off += 3121152;
  float* hbuf = ws + off; off += 16384;
  float* zbuf = ws + off; off += 2048;
  int* ctrl = (int*)(ws + off); off += 1024;  // cnt_e[8*64] cnt_d[8*64]
  int* cnt_e = ctrl;
  int* cnt_d = ctrl + 512;
  unsigned short* hseq_bf = (unsigned short*)(ws + off); off += 524288;
  size_t wbf_elems = (size_t)Vv * Hh;
  bool use_wbf = (off + wbf_elems / 2) * sizeof(float) <= ws_size;
  unsigned short* wbf = (unsigned short*)(ws + off);

  // init
  hipMemsetAsync(ctrl, 0, 1024 * sizeof(int), stream);
  k_zero<<<(Bb * Hh + 255) / 256, 256, 0, stream>>>(hbuf, Bb * Hh);
  k_zero_first<<<(Bb * Vv + 255) / 256, 256, 0, stream>>>(out);

  if (use_wbf)
    k_cvt_bf16<<<(int)((wbf_elems / 4 + 255) / 256), 256, 0, stream>>>(
        dec_fcW, wbf, (int)(wbf_elems / 4));

  dim3 tb(32, 8);
  k_transpose<<<dim3(256 / 32, 1536 / 32), tb, 0, stream>>>(enc_Wih, wihT_e, 1536, 256);
  k_transpose<<<dim3(256 / 32, 1536 / 32), tb, 0, stream>>>(dec_Wih, wihT_d, 1536, 256);

  // gx_e (decoder gx fused into the encoder-scan launch)
  k_gx<<<128 * 6, 256, 0, stream>>>(x, enc_emb, wihT_e, enc_bih, gx_e);

  // encoder scan (64 WGs) + gx_d (762 WGs)
  k_enc_fused<<<NWG + 762, 256, 0, stream>>>(enc_Whh, enc_bhh, gx_e, hbuf, cnt_e,
                                             x, dec_emb, wihT_d, dec_bih, gx_d);

  k_z<<<16, 128, 0, stream>>>(hbuf, fc_enc_W, fc_enc_b, zbuf, out + (size_t)Bb * Tt * Vv);
  k_hid0<<<16, 512, 0, stream>>>(zbuf, fc_dec_W, fc_dec_b, hbuf);

  // decoder scan (standalone)
  k_dec_scan<<<NWG, 256, 0, stream>>>(dec_Whh, dec_bhh, gx_d, hbuf, hseq_bf, cnt_d);

  // logits (standalone)
  if (use_wbf)
    k_logits_mfma<true><<<dim3(Vv / 64, 8), 256, 0, stream>>>(hseq_bf, wbf, dec_fcW,
                                                              dec_fcb, out);
  else
    k_logits_mfma<false><<<dim3(Vv / 64, 8), 256, 0, stream>>>(hseq_bf, (unsigned short*)nullptr,
                                                               dec_fcW, dec_fcb, out);
}

// Round 10
// 1729.587 us; speedup vs baseline: 1.2462x; 1.0056x over previous
//
#include <hip/hip_runtime.h>

#define Vv 32000
#define Ee 256
#define Hh 512
#define Ll 128
#define Bb 16
#define Tt 128
#define G3 1536   // 3*H
#define NWG 64    // 2 groups x 32 WGs

typedef __attribute__((ext_vector_type(8))) short short8;
typedef __attribute__((ext_vector_type(4))) float f32x4;

__device__ __forceinline__ float sigmoidf_(float x) { return 1.f / (1.f + __expf(-x)); }

__device__ __forceinline__ unsigned short f2bf(float f) {
  unsigned int u = __float_as_uint(f);
  u = (u + 0x7fffu + ((u >> 16) & 1u)) >> 16;
  return (unsigned short)u;
}

// ---------------- small helpers ----------------
__global__ void k_zero(float* __restrict__ p, int n) {
  int i = blockIdx.x * 256 + threadIdx.x;
  if (i < n) p[i] = 0.f;
}

__global__ void k_zero_first(float* __restrict__ out) {
  int idx = blockIdx.x * 256 + threadIdx.x;
  if (idx < Bb * Vv) {
    int b = idx / Vv, v = idx % Vv;
    out[(size_t)b * Tt * Vv + v] = 0.f;
  }
}

__global__ void k_cvt_bf16(const float* __restrict__ in, unsigned short* __restrict__ out,
                           int n4) {
  int i = blockIdx.x * 256 + threadIdx.x;
  if (i < n4) {
    float4 v = ((const float4*)in)[i];
    ushort4 o;
    o.x = f2bf(v.x); o.y = f2bf(v.y); o.z = f2bf(v.z); o.w = f2bf(v.w);
    ((ushort4*)out)[i] = o;
  }
}

__global__ void k_transpose(const float* __restrict__ in, float* __restrict__ out,
                            int R, int C) {
  __shared__ float tile[32][33];
  int c = blockIdx.x * 32 + threadIdx.x;
  int r0 = blockIdx.y * 32;
  for (int i = threadIdx.y; i < 32; i += 8)
    tile[i][threadIdx.x] = in[(size_t)(r0 + i) * C + c];
  __syncthreads();
  int r = r0 + threadIdx.x;
  int c0 = blockIdx.x * 32;
  for (int i = threadIdx.y; i < 32; i += 8)
    out[(size_t)(c0 + i) * R + r] = tile[threadIdx.x][i];
}

// ---------------- gx body ----------------
__device__ __forceinline__ void gx_body(int e, const int* __restrict__ x,
                                        const float* __restrict__ emb,
                                        const float* __restrict__ WihT,
                                        const float* __restrict__ b_ih,
                                        float* __restrict__ gx) {
  __shared__ float A[16][Ee];
  int mt = e / 6, gy = e % 6;
  int g = gy * 256 + threadIdx.x;
  for (int i = 0; i < 16; i++) {
    int tok = x[i * Tt + mt];
    A[i][threadIdx.x] = emb[(size_t)tok * Ee + threadIdx.x];
  }
  __syncthreads();
  float acc[16];
  float bg = b_ih[g];
#pragma unroll
  for (int i = 0; i < 16; i++) acc[i] = bg;
#pragma unroll 4
  for (int ee = 0; ee < Ee; ee++) {
    float w = WihT[(size_t)ee * G3 + g];
#pragma unroll
    for (int i = 0; i < 16; i++) acc[i] = fmaf(A[i][ee], w, acc[i]);
  }
#pragma unroll
  for (int i = 0; i < 16; i++)
    gx[(size_t)(mt * 16 + i) * G3 + g] = acc[i];
}

__global__ void k_gx(const int* __restrict__ x, const float* __restrict__ emb,
                     const float* __restrict__ WihT, const float* __restrict__ b_ih,
                     float* __restrict__ gx) {
  gx_body(blockIdx.x, x, emb, WihT, b_ih, gx);
}

// ---------------- scan body: 2 groups x 32 WGs, batch-split, interleaved-k ----------------
// Group g = wg>>5 owns batches g*8..g*8+7.  WG wgl = wg&31 owns cols wgl*16..+15.
// lane = ks(4b)<<2 | jl(2b); wave = jh (col block).  j = wgl*16 + jh*4 + jl.
// Lane k-set: {ks*4 + q*64 + e} (interleaved: bank-conflict-free, 2-way alias).
// k-reduce: shfl_xor over lane bits 2..5.  Gate lanes ks<8 finish (b=g*8+ks, j).
template <bool HSEQ>
__device__ __forceinline__ void scan_body(
    const float* __restrict__ Whh, const float* __restrict__ bhh,
    const float* __restrict__ gx, float* __restrict__ hbuf,
    unsigned short* __restrict__ hseq, int nsteps,
    int* __restrict__ cnt) {   // 8 lines x 64 ints; group g uses lines g*4..g*4+3
  __shared__ float h_lds[8 * Hh];   // 16 KB (this group's 8 batches)
  const int tid = threadIdx.x;
  const int wg = blockIdx.x;
  const int g = wg >> 5;
  const int wgl = wg & 31;
  const int lane = tid & 63;
  const int jh = tid >> 6;       // wave = col block
  const int jl = lane & 3;
  const int ks = lane >> 2;      // 0..15
  const int j = wgl * 16 + jh * 4 + jl;
  const int bsel = g * 8 + ks;   // gate-lane global batch (valid when ks<8)
  const bool gate = (ks < 8);

  // weights: 3 gates x 32 interleaved k in f32 regs (96 VGPRs)
  float wr[32], wz[32], wn[32];
  {
    const float* R = Whh + (size_t)j * Hh;
    const float* Z = Whh + (size_t)(Hh + j) * Hh;
    const float* N = Whh + (size_t)(2 * Hh + j) * Hh;
#pragma unroll
    for (int q = 0; q < 8; ++q) {
      int k = ks * 4 + q * 64;
      float4 a = *(const float4*)(R + k);
      float4 b = *(const float4*)(Z + k);
      float4 c = *(const float4*)(N + k);
      wr[4*q] = a.x; wr[4*q+1] = a.y; wr[4*q+2] = a.z; wr[4*q+3] = a.w;
      wz[4*q] = b.x; wz[4*q+1] = b.y; wz[4*q+2] = b.z; wz[4*q+3] = b.w;
      wn[4*q] = c.x; wn[4*q+1] = c.y; wn[4*q+2] = c.z; wn[4*q+3] = c.w;
    }
  }
  const float bhr = bhh[j], bhz = bhh[Hh + j], bhn = bhh[2 * Hh + j];

  // gx for step 0 (gate lanes)
  float xr = 0.f, xz = 0.f, xn = 0.f;
  if (gate) {
    const float* gp = gx + (size_t)bsel * G3 + j;
    xr = gp[0]; xz = gp[Hh]; xn = gp[2 * Hh];
  }

  for (int t = 0; t < nsteps; ++t) {
    // ---- stage this group's h(t) -> LDS (sc1 wide loads: LLC-fresh) ----
    {
      const f32x4* hsrc =
          (const f32x4*)(hbuf + (size_t)(t & 1) * (Bb * Hh) + (size_t)g * 8 * Hh);
      f32x4 hv[4];
#pragma unroll
      for (int i = 0; i < 4; ++i) {
        const f32x4* p = hsrc + tid + 256 * i;
        asm volatile("global_load_dwordx4 %0, %1, off sc1" : "=v"(hv[i]) : "v"(p));
      }
      asm volatile("s_waitcnt vmcnt(0)" ::: "memory");
      f32x4* hl = (f32x4*)h_lds;
#pragma unroll
      for (int i = 0; i < 4; ++i) hl[tid + 256 * i] = hv[i];
    }
    __syncthreads();

    // ---- per-lane partial dots (reg weights x LDS h, interleaved k) ----
    float accR[8], accZ[8], accN[8];
#pragma unroll
    for (int b8 = 0; b8 < 8; ++b8) { accR[b8] = 0.f; accZ[b8] = 0.f; accN[b8] = 0.f; }
#pragma unroll
    for (int b8 = 0; b8 < 8; ++b8) {
      const float* hb = h_lds + b8 * Hh + ks * 4;
#pragma unroll
      for (int q = 0; q < 8; ++q) {
        float4 hv = *(const float4*)(hb + q * 64);
        accR[b8] = fmaf(wr[4*q+0], hv.x, accR[b8]);
        accR[b8] = fmaf(wr[4*q+1], hv.y, accR[b8]);
        accR[b8] = fmaf(wr[4*q+2], hv.z, accR[b8]);
        accR[b8] = fmaf(wr[4*q+3], hv.w, accR[b8]);
        accZ[b8] = fmaf(wz[4*q+0], hv.x, accZ[b8]);
        accZ[b8] = fmaf(wz[4*q+1], hv.y, accZ[b8]);
        accZ[b8] = fmaf(wz[4*q+2], hv.z, accZ[b8]);
        accZ[b8] = fmaf(wz[4*q+3], hv.w, accZ[b8]);
        accN[b8] = fmaf(wn[4*q+0], hv.x, accN[b8]);
        accN[b8] = fmaf(wn[4*q+1], hv.y, accN[b8]);
        accN[b8] = fmaf(wn[4*q+2], hv.z, accN[b8]);
        accN[b8] = fmaf(wn[4*q+3], hv.w, accN[b8]);
      }
    }
    // ---- reduce over ks (lane bits 2..5), fully within wave ----
#pragma unroll
    for (int b8 = 0; b8 < 8; ++b8) {
      accR[b8] += __shfl_xor(accR[b8], 4, 64);
      accR[b8] += __shfl_xor(accR[b8], 8, 64);
      accR[b8] += __shfl_xor(accR[b8], 16, 64);
      accR[b8] += __shfl_xor(accR[b8], 32, 64);
      accZ[b8] += __shfl_xor(accZ[b8], 4, 64);
      accZ[b8] += __shfl_xor(accZ[b8], 8, 64);
      accZ[b8] += __shfl_xor(accZ[b8], 16, 64);
      accZ[b8] += __shfl_xor(accZ[b8], 32, 64);
      accN[b8] += __shfl_xor(accN[b8], 4, 64);
      accN[b8] += __shfl_xor(accN[b8], 8, 64);
      accN[b8] += __shfl_xor(accN[b8], 16, 64);
      accN[b8] += __shfl_xor(accN[b8], 32, 64);
    }
    // static-index batch select: gate lane ks takes acc[ks]
    float ar = 0.f, az = 0.f, an_ = 0.f;
#pragma unroll
    for (int b8 = 0; b8 < 8; ++b8)
      if (ks == b8) { ar = accR[b8]; az = accZ[b8]; an_ = accN[b8]; }

    float* hdst = hbuf + (size_t)((t + 1) & 1) * (Bb * Hh);
    if (gate) {
      float r = sigmoidf_(xr + ar + bhr);
      float u = sigmoidf_(xz + az + bhz);
      float n = tanhf(xn + r * (an_ + bhn));
      float hold = h_lds[ks * Hh + j];
      float hnew = (1.f - u) * n + u * hold;
      __hip_atomic_store((int*)hdst + bsel * Hh + j, __float_as_int(hnew),
                         __ATOMIC_RELAXED, __HIP_MEMORY_SCOPE_AGENT);
      if (HSEQ) hseq[((size_t)t * Bb + bsel) * Hh + j] = f2bf(hnew);
    }

    // ---- per-group barrier: drain, split-counter arrive, bounded parallel poll ----
    if (t < nsteps - 1) {
      asm volatile("s_waitcnt vmcnt(0)" ::: "memory");
      __syncthreads();
      if (tid == 0)
        __hip_atomic_fetch_add(&cnt[64 * (g * 4 + (wgl & 3))], 1, __ATOMIC_RELAXED,
                               __HIP_MEMORY_SCOPE_AGENT);
      if (gate) {  // prefetch next step's gx under the wait
        const float* gp = gx + (size_t)((t + 1) * Bb + bsel) * G3 + j;
        xr = gp[0]; xz = gp[Hh]; xn = gp[2 * Hh];
      }
      if (tid < 64) {
        const int tgt = (t + 1) * 8;
        int* myc = cnt + 64 * (g * 4 + (tid & 3));
        for (int it = 0; it < 100000; ++it) {
          int v;
          asm volatile("global_load_dword %0, %1, off sc1\n\ts_waitcnt vmcnt(0)"
                       : "=v"(v) : "v"(myc) : "memory");
          if (__all(v >= tgt)) break;
        }
      }
      __syncthreads();
    }
  }
}

// ---------------- fused enc kernel: scan + decoder gx ----------------
__global__ void __launch_bounds__(256, 1) k_enc_fused(
    const float* __restrict__ Whh, const float* __restrict__ bhh,
    const float* __restrict__ gx_e, float* __restrict__ hbuf,
    int* __restrict__ cnt,
    const int* __restrict__ x, const float* __restrict__ dec_emb,
    const float* __restrict__ wihT_d, const float* __restrict__ dec_bih,
    float* __restrict__ gx_d) {
  if (blockIdx.x < NWG)
    scan_body<false>(Whh, bhh, gx_e, hbuf, (unsigned short*)nullptr, Tt, cnt);
  else
    gx_body(blockIdx.x - NWG, x, dec_emb, wihT_d, dec_bih, gx_d);
}

// ---------------- standalone decoder scan ----------------
__global__ void __launch_bounds__(256, 1) k_dec_scan(
    const float* __restrict__ Whh, const float* __restrict__ bhh,
    const float* __restrict__ gx_d, float* __restrict__ hbuf,
    unsigned short* __restrict__ hseq, int* __restrict__ cnt) {
  scan_body<true>(Whh, bhh, gx_d, hbuf, hseq, Tt - 1, cnt);
}

// ---------------- z and hid0 ----------------
__global__ void k_z(const float* __restrict__ h, const float* __restrict__ W,
                    const float* __restrict__ bias, float* __restrict__ zws,
                    float* __restrict__ zout) {
  int b = blockIdx.x;
  int l = threadIdx.x;  // 128
  __shared__ float hsh[Hh];
  for (int i = threadIdx.x; i < Hh; i += 128) hsh[i] = h[b * Hh + i];
  __syncthreads();
  float acc = bias[l];
#pragma unroll 4
  for (int k = 0; k < Hh; k++) acc = fmaf(hsh[k], W[(size_t)l * Hh + k], acc);
  zws[b * Ll + l] = acc;
  zout[b * Ll + l] = acc;
}

__global__ void k_hid0(const float* __restrict__ z, const float* __restrict__ W,
                       const float* __restrict__ bias, float* __restrict__ h0) {
  int b = blockIdx.x;
  int j = threadIdx.x;  // 512
  __shared__ float zsh[Ll];
  if (threadIdx.x < Ll) zsh[threadIdx.x] = z[b * Ll + threadIdx.x];
  __syncthreads();
  float acc = bias[j];
#pragma unroll 4
  for (int l = 0; l < Ll; l++) acc = fmaf(zsh[l], W[(size_t)j * Ll + l], acc);
  h0[b * Hh + j] = tanhf(acc);
}

// ---------------- logits via MFMA bf16 (standalone) ----------------
template <bool BF16W>
__global__ void __launch_bounds__(256) k_logits_mfma(
    const unsigned short* __restrict__ Abf,  // [2048][512] bf16
    const unsigned short* __restrict__ Wbf,  // [32000][512] bf16 (if BF16W)
    const float* __restrict__ Wf,            // [32000][512] f32 (fallback)
    const float* __restrict__ bias, float* __restrict__ out) {
  const int tid = threadIdx.x;
  const int wid = tid >> 6, lane = tid & 63;
  const int ln = lane & 15, hi = lane >> 4;
  const int n0 = blockIdx.x * 64;
  const int m0 = blockIdx.y * 256 + wid * 64;
  f32x4 acc[4][4];
#pragma unroll
  for (int mi = 0; mi < 4; ++mi)
#pragma unroll
    for (int ni = 0; ni < 4; ++ni) acc[mi][ni] = (f32x4)0.f;

  const unsigned short* ap = Abf + (size_t)(m0 + ln) * Hh + hi * 8;
  const unsigned short* bp16 = Wbf + (size_t)(n0 + ln) * Hh + hi * 8;
  const float* bp32 = Wf + (size_t)(n0 + ln) * Hh + hi * 8;

  for (int kt = 0; kt < 16; ++kt) {
    short8 a[4], b[4];
#pragma unroll
    for (int mi = 0; mi < 4; ++mi)
      a[mi] = *(const short8*)(ap + (size_t)mi * 16 * Hh + kt * 32);
#pragma unroll
    for (int ni = 0; ni < 4; ++ni) {
      if (BF16W) {
        b[ni] = *(const short8*)(bp16 + (size_t)ni * 16 * Hh + kt * 32);
      } else {
        const float* q = bp32 + (size_t)ni * 16 * Hh + kt * 32;
        short8 tv;
#pragma unroll
        for (int e = 0; e < 8; ++e) tv[e] = (short)f2bf(q[e]);
        b[ni] = tv;
      }
    }
#pragma unroll
    for (int mi = 0; mi < 4; ++mi)
#pragma unroll
      for (int ni = 0; ni < 4; ++ni)
        acc[mi][ni] = __builtin_amdgcn_mfma_f32_16x16x32_bf16(a[mi], b[ni], acc[mi][ni], 0, 0, 0);
  }

#pragma unroll
  for (int ni = 0; ni < 4; ++ni) {
    int n = n0 + ni * 16 + ln;
    float bv = bias[n];
#pragma unroll
    for (int mi = 0; mi < 4; ++mi) {
      int mbase = m0 + mi * 16 + hi * 4;
#pragma unroll
      for (int r = 0; r < 4; ++r) {
        int m = mbase + r;
        if (m < 2032) {
          int t = m >> 4, bb = m & 15;
          out[((size_t)(bb * Tt + 1 + t)) * Vv + n] = acc[mi][ni][r] + bv;
        }
      }
    }
  }
}

extern "C" void kernel_launch(void* const* d_in, const int* in_sizes, int n_in,
                              void* d_out, int out_size, void* d_ws, size_t ws_size,
                              hipStream_t stream) {
  const int* x = (const int*)d_in[0];
  const float* enc_emb = (const float*)d_in[1];
  const float* enc_Wih = (const float*)d_in[2];
  const float* enc_bih = (const float*)d_in[3];
  const float* enc_Whh = (const float*)d_in[4];
  const float* enc_bhh = (const float*)d_in[5];
  const float* fc_enc_W = (const float*)d_in[6];
  const float* fc_enc_b = (const float*)d_in[7];
  const float* fc_dec_W = (const float*)d_in[8];
  const float* fc_dec_b = (const float*)d_in[9];
  const float* dec_emb = (const float*)d_in[10];
  const float* dec_Wih = (const float*)d_in[11];
  const float* dec_bih = (const float*)d_in[12];
  const float* dec_Whh = (const float*)d_in[13];
  const float* dec_bhh = (const float*)d_in[14];
  const float* dec_fcW = (const float*)d_in[15];
  const float* dec_fcb = (const float*)d_in[16];
  float* out = (float*)d_out;

  float* ws = (float*)d_ws;
  size_t off = 0;
  float* wihT_e = ws + off; off += 393216;
  float* wihT_d = ws + off; off += 393216;
  float* gx_e = ws + off; off += 3145728;
  float* gx_d = ws + off; off += 3121152;
  float* hbuf = ws + off; off += 16384;
  float* zbuf = ws + off; off += 2048;
  int* ctrl = (int*)(ws + off); off += 1024;  // cnt_e[8*64] cnt_d[8*64]
  int* cnt_e = ctrl;
  int* cnt_d = ctrl + 512;
  unsigned short* hseq_bf = (unsigned short*)(ws + off); off += 524288;
  size_t wbf_elems = (size_t)Vv * Hh;
  bool use_wbf = (off + wbf_elems / 2) * sizeof(float) <= ws_size;
  unsigned short* wbf = (unsigned short*)(ws + off);

  // init
  hipMemsetAsync(ctrl, 0, 1024 * sizeof(int), stream);
  k_zero<<<(Bb * Hh + 255) / 256, 256, 0, stream>>>(hbuf, Bb * Hh);
  k_zero_first<<<(Bb * Vv + 255) / 256, 256, 0, stream>>>(out);

  if (use_wbf)
    k_cvt_bf16<<<(int)((wbf_elems / 4 + 255) / 256), 256, 0, stream>>>(
        dec_fcW, wbf, (int)(wbf_elems / 4));

  dim3 tb(32, 8);
  k_transpose<<<dim3(256 / 32, 1536 / 32), tb, 0, stream>>>(enc_Wih, wihT_e, 1536, 256);
  k_transpose<<<dim3(256 / 32, 1536 / 32), tb, 0, stream>>>(dec_Wih, wihT_d, 1536, 256);

  // gx_e (decoder gx fused into the encoder-scan launch)
  k_gx<<<128 * 6, 256, 0, stream>>>(x, enc_emb, wihT_e, enc_bih, gx_e);

  // encoder scan (64 WGs, 2 groups) + gx_d (762 WGs)
  k_enc_fused<<<NWG + 762, 256, 0, stream>>>(enc_Whh, enc_bhh, gx_e, hbuf, cnt_e,
                                             x, dec_emb, wihT_d, dec_bih, gx_d);

  k_z<<<16, 128, 0, stream>>>(hbuf, fc_enc_W, fc_enc_b, zbuf, out + (size_t)Bb * Tt * Vv);
  k_hid0<<<16, 512, 0, stream>>>(zbuf, fc_dec_W, fc_dec_b, hbuf);

  // decoder scan (standalone, 2 groups)
  k_dec_scan<<<NWG, 256, 0, stream>>>(dec_Whh, dec_bhh, gx_d, hbuf, hseq_bf, cnt_d);

  // logits (standalone)
  if (use_wbf)
    k_logits_mfma<true><<<dim3(Vv / 64, 8), 256, 0, stream>>>(hseq_bf, wbf, dec_fcW,
                                                              dec_fcb, out);
  else
    k_logits_mfma<false><<<dim3(Vv / 64, 8), 256, 0, stream>>>(hseq_bf, (unsigned short*)nullptr,
                                                               dec_fcW, dec_fcb, out);
}

// Round 11
// 1079.270 us; speedup vs baseline: 1.9971x; 1.6026x over previous
//
#include <hip/hip_runtime.h>

#define Vv 32000
#define Ee 256
#define Hh 512
#define Ll 128
#define Bb 16
#define Tt 128
#define G3 1536   // 3*H
#define NSW 256   // scan WGs: 16 groups x 16 WGs

typedef __attribute__((ext_vector_type(8))) short short8;
typedef __attribute__((ext_vector_type(4))) float f32x4;

__device__ __forceinline__ float sigmoidf_(float x) { return 1.f / (1.f + __expf(-x)); }

__device__ __forceinline__ unsigned short f2bf(float f) {
  unsigned int u = __float_as_uint(f);
  u = (u + 0x7fffu + ((u >> 16) & 1u)) >> 16;
  return (unsigned short)u;
}

// ---------------- small helpers ----------------
__global__ void k_zero(float* __restrict__ p, int n) {
  int i = blockIdx.x * 256 + threadIdx.x;
  if (i < n) p[i] = 0.f;
}

__global__ void k_zero_first(float* __restrict__ out) {
  int idx = blockIdx.x * 256 + threadIdx.x;
  if (idx < Bb * Vv) {
    int b = idx / Vv, v = idx % Vv;
    out[(size_t)b * Tt * Vv + v] = 0.f;
  }
}

__global__ void k_cvt_bf16(const float* __restrict__ in, unsigned short* __restrict__ out,
                           int n4) {
  int i = blockIdx.x * 256 + threadIdx.x;
  if (i < n4) {
    float4 v = ((const float4*)in)[i];
    ushort4 o;
    o.x = f2bf(v.x); o.y = f2bf(v.y); o.z = f2bf(v.z); o.w = f2bf(v.w);
    ((ushort4*)out)[i] = o;
  }
}

__global__ void k_transpose(const float* __restrict__ in, float* __restrict__ out,
                            int R, int C) {
  __shared__ float tile[32][33];
  int c = blockIdx.x * 32 + threadIdx.x;
  int r0 = blockIdx.y * 32;
  for (int i = threadIdx.y; i < 32; i += 8)
    tile[i][threadIdx.x] = in[(size_t)(r0 + i) * C + c];
  __syncthreads();
  int r = r0 + threadIdx.x;
  int c0 = blockIdx.x * 32;
  for (int i = threadIdx.y; i < 32; i += 8)
    out[(size_t)(c0 + i) * R + r] = tile[threadIdx.x][i];
}

// ---------------- gx body ----------------
__device__ __forceinline__ void gx_body(int e, const int* __restrict__ x,
                                        const float* __restrict__ emb,
                                        const float* __restrict__ WihT,
                                        const float* __restrict__ b_ih,
                                        float* __restrict__ gx) {
  __shared__ float A[16][Ee];
  int mt = e / 6, gy = e % 6;
  int g = gy * 256 + threadIdx.x;
  for (int i = 0; i < 16; i++) {
    int tok = x[i * Tt + mt];
    A[i][threadIdx.x] = emb[(size_t)tok * Ee + threadIdx.x];
  }
  __syncthreads();
  float acc[16];
  float bg = b_ih[g];
#pragma unroll
  for (int i = 0; i < 16; i++) acc[i] = bg;
#pragma unroll 4
  for (int ee = 0; ee < Ee; ee++) {
    float w = WihT[(size_t)ee * G3 + g];
#pragma unroll
    for (int i = 0; i < 16; i++) acc[i] = fmaf(A[i][ee], w, acc[i]);
  }
#pragma unroll
  for (int i = 0; i < 16; i++)
    gx[(size_t)(mt * 16 + i) * G3 + g] = acc[i];
}

__global__ void k_gx(const int* __restrict__ x, const float* __restrict__ emb,
                     const float* __restrict__ WihT, const float* __restrict__ b_ih,
                     float* __restrict__ gx) {
  gx_body(blockIdx.x, x, emb, WihT, b_ih, gx);
}

// ---------------- scan body: 16 groups (1 batch each) x 16 WGs (32 cols) ----------------
// wg: g = wg>>4 (batch), wgl = wg&15 (col block). tid: wave=tid>>6, cl=(lane>>3), ks=lane&7.
// j = wgl*32 + wave*8 + cl. Lane k-set {ks*4 + q*32 + e}: LDS broadcast, conflict-free.
// k-reduce: shfl_xor 1,2,4 (lane bits 0..2). Gate lane ks==0 finishes col j of batch g.
// Barrier: per-WG flag STORE (no RMW) into group's 64B line; 4-lane dwordx4 poll.
template <bool HSEQ>
__device__ __forceinline__ void scan_body(
    const float* __restrict__ Whh, const float* __restrict__ bhh,
    const float* __restrict__ gx, float* __restrict__ hbuf,
    unsigned short* __restrict__ hseq, int nsteps,
    int* __restrict__ flg) {   // 16 groups x 64 ints (use first 16 of each line)
  __shared__ float h_lds[Hh];   // 2 KB: this group's batch h
  const int tid = threadIdx.x;
  const int wg = blockIdx.x;
  const int g = wg >> 4;
  const int wgl = wg & 15;
  const int wave = tid >> 6;
  const int lane = tid & 63;
  const int cl = lane >> 3;    // 0..7
  const int ks = lane & 7;     // 0..7
  const int j = wgl * 32 + wave * 8 + cl;
  const bool gate = (ks == 0);

  // weights: 3 gates x 64 interleaved k in f32 regs (192 VGPRs)
  float wr[64], wz[64], wn[64];
  {
    const float* R = Whh + (size_t)j * Hh + ks * 4;
    const float* Z = R + (size_t)Hh * Hh;
    const float* N = Z + (size_t)Hh * Hh;
#pragma unroll
    for (int q = 0; q < 16; ++q) {
      float4 a = *(const float4*)(R + q * 32);
      float4 b = *(const float4*)(Z + q * 32);
      float4 c = *(const float4*)(N + q * 32);
      wr[4*q] = a.x; wr[4*q+1] = a.y; wr[4*q+2] = a.z; wr[4*q+3] = a.w;
      wz[4*q] = b.x; wz[4*q+1] = b.y; wz[4*q+2] = b.z; wz[4*q+3] = b.w;
      wn[4*q] = c.x; wn[4*q+1] = c.y; wn[4*q+2] = c.z; wn[4*q+3] = c.w;
    }
  }
  float bhr = 0.f, bhz = 0.f, bhn = 0.f;
  if (gate) { bhr = bhh[j]; bhz = bhh[Hh + j]; bhn = bhh[2 * Hh + j]; }

  // gx for step 0 (gate lanes); row m = t*16 + g
  float xr = 0.f, xz = 0.f, xn = 0.f;
  if (gate) {
    const float* gp = gx + (size_t)g * G3 + j;
    xr = gp[0]; xz = gp[Hh]; xn = gp[2 * Hh];
  }

  for (int t = 0; t < nsteps; ++t) {
    // ---- stage this batch's h(t) -> LDS (sc1 wide loads: LLC-fresh) ----
    if (tid < 128) {
      const f32x4* p =
          (const f32x4*)(hbuf + (size_t)(t & 1) * (Bb * Hh) + (size_t)g * Hh) + tid;
      f32x4 hv;
      asm volatile("global_load_dwordx4 %0, %1, off sc1" : "=v"(hv) : "v"(p));
      asm volatile("s_waitcnt vmcnt(0)" ::: "memory");
      ((f32x4*)h_lds)[tid] = hv;
    }
    __syncthreads();

    // ---- per-lane partial dots (reg weights x LDS h broadcast) ----
    float aR = 0.f, aZ = 0.f, aN = 0.f;
    {
      const float* hb = h_lds + ks * 4;
#pragma unroll
      for (int q = 0; q < 16; ++q) {
        float4 hv = *(const float4*)(hb + q * 32);
        aR = fmaf(wr[4*q+0], hv.x, aR);
        aR = fmaf(wr[4*q+1], hv.y, aR);
        aR = fmaf(wr[4*q+2], hv.z, aR);
        aR = fmaf(wr[4*q+3], hv.w, aR);
        aZ = fmaf(wz[4*q+0], hv.x, aZ);
        aZ = fmaf(wz[4*q+1], hv.y, aZ);
        aZ = fmaf(wz[4*q+2], hv.z, aZ);
        aZ = fmaf(wz[4*q+3], hv.w, aZ);
        aN = fmaf(wn[4*q+0], hv.x, aN);
        aN = fmaf(wn[4*q+1], hv.y, aN);
        aN = fmaf(wn[4*q+2], hv.z, aN);
        aN = fmaf(wn[4*q+3], hv.w, aN);
      }
    }
    // ---- reduce over ks (lane bits 0..2), fully within wave ----
    aR += __shfl_xor(aR, 1, 64); aR += __shfl_xor(aR, 2, 64); aR += __shfl_xor(aR, 4, 64);
    aZ += __shfl_xor(aZ, 1, 64); aZ += __shfl_xor(aZ, 2, 64); aZ += __shfl_xor(aZ, 4, 64);
    aN += __shfl_xor(aN, 1, 64); aN += __shfl_xor(aN, 2, 64); aN += __shfl_xor(aN, 4, 64);

    // ---- gate finish + publish ----
    float* hdst = hbuf + (size_t)((t + 1) & 1) * (Bb * Hh) + (size_t)g * Hh;
    if (gate) {
      float r = sigmoidf_(xr + aR + bhr);
      float u = sigmoidf_(xz + aZ + bhz);
      float n = tanhf(xn + r * (aN + bhn));
      float hold = h_lds[j];
      float hnew = (1.f - u) * n + u * hold;
      __hip_atomic_store((int*)hdst + j, __float_as_int(hnew),
                         __ATOMIC_RELAXED, __HIP_MEMORY_SCOPE_AGENT);
      if (HSEQ) hseq[((size_t)t * Bb + g) * Hh + j] = f2bf(hnew);
    }

    // ---- group barrier: drain -> flag STORE -> 4-lane dwordx4 poll ----
    if (t < nsteps - 1) {
      asm volatile("s_waitcnt vmcnt(0)" ::: "memory");
      __syncthreads();
      if (tid == 0)
        __hip_atomic_store(&flg[g * 64 + wgl], t + 1,
                           __ATOMIC_RELAXED, __HIP_MEMORY_SCOPE_AGENT);
      if (gate) {  // prefetch next step's gx under the wait
        const float* gp = gx + (size_t)((t + 1) * Bb + g) * G3 + j;
        xr = gp[0]; xz = gp[Hh]; xn = gp[2 * Hh];
      }
      if (tid < 64) {
        const int tgt = t + 1;
        const uint4* base = (const uint4*)(flg + g * 64) + lane;  // lanes 0..3
        for (int it = 0; it < 100000; ++it) {
          uint4 v;
          bool ok = true;
          if (lane < 4) {
            asm volatile("global_load_dwordx4 %0, %1, off sc1\n\ts_waitcnt vmcnt(0)"
                         : "=v"(v) : "v"(base) : "memory");
            ok = ((int)v.x >= tgt) & ((int)v.y >= tgt) &
                 ((int)v.z >= tgt) & ((int)v.w >= tgt);
          }
          if (__all(ok)) break;
        }
      }
      __syncthreads();
    }
  }
}

// ---------------- fused enc kernel: scan + decoder gx ----------------
__global__ void __launch_bounds__(256, 1) k_enc_fused(
    const float* __restrict__ Whh, const float* __restrict__ bhh,
    const float* __restrict__ gx_e, float* __restrict__ hbuf,
    int* __restrict__ flg,
    const int* __restrict__ x, const float* __restrict__ dec_emb,
    const float* __restrict__ wihT_d, const float* __restrict__ dec_bih,
    float* __restrict__ gx_d) {
  if (blockIdx.x < NSW)
    scan_body<false>(Whh, bhh, gx_e, hbuf, (unsigned short*)nullptr, Tt, flg);
  else
    gx_body(blockIdx.x - NSW, x, dec_emb, wihT_d, dec_bih, gx_d);
}

// ---------------- standalone decoder scan ----------------
__global__ void __launch_bounds__(256, 1) k_dec_scan(
    const float* __restrict__ Whh, const float* __restrict__ bhh,
    const float* __restrict__ gx_d, float* __restrict__ hbuf,
    unsigned short* __restrict__ hseq, int* __restrict__ flg) {
  scan_body<true>(Whh, bhh, gx_d, hbuf, hseq, Tt - 1, flg);
}

// ---------------- z and hid0 ----------------
__global__ void k_z(const float* __restrict__ h, const float* __restrict__ W,
                    const float* __restrict__ bias, float* __restrict__ zws,
                    float* __restrict__ zout) {
  int b = blockIdx.x;
  int l = threadIdx.x;  // 128
  __shared__ float hsh[Hh];
  for (int i = threadIdx.x; i < Hh; i += 128) hsh[i] = h[b * Hh + i];
  __syncthreads();
  float acc = bias[l];
#pragma unroll 4
  for (int k = 0; k < Hh; k++) acc = fmaf(hsh[k], W[(size_t)l * Hh + k], acc);
  zws[b * Ll + l] = acc;
  zout[b * Ll + l] = acc;
}

__global__ void k_hid0(const float* __restrict__ z, const float* __restrict__ W,
                       const float* __restrict__ bias, float* __restrict__ h0) {
  int b = blockIdx.x;
  int j = threadIdx.x;  // 512
  __shared__ float zsh[Ll];
  if (threadIdx.x < Ll) zsh[threadIdx.x] = z[b * Ll + threadIdx.x];
  __syncthreads();
  float acc = bias[j];
#pragma unroll 4
  for (int l = 0; l < Ll; l++) acc = fmaf(zsh[l], W[(size_t)j * Ll + l], acc);
  h0[b * Hh + j] = tanhf(acc);
}

// ---------------- logits via MFMA bf16 (standalone) ----------------
template <bool BF16W>
__global__ void __launch_bounds__(256) k_logits_mfma(
    const unsigned short* __restrict__ Abf,  // [2048][512] bf16
    const unsigned short* __restrict__ Wbf,  // [32000][512] bf16 (if BF16W)
    const float* __restrict__ Wf,            // [32000][512] f32 (fallback)
    const float* __restrict__ bias, float* __restrict__ out) {
  const int tid = threadIdx.x;
  const int wid = tid >> 6, lane = tid & 63;
  const int ln = lane & 15, hi = lane >> 4;
  const int n0 = blockIdx.x * 64;
  const int m0 = blockIdx.y * 256 + wid * 64;
  f32x4 acc[4][4];
#pragma unroll
  for (int mi = 0; mi < 4; ++mi)
#pragma unroll
    for (int ni = 0; ni < 4; ++ni) acc[mi][ni] = (f32x4)0.f;

  const unsigned short* ap = Abf + (size_t)(m0 + ln) * Hh + hi * 8;
  const unsigned short* bp16 = Wbf + (size_t)(n0 + ln) * Hh + hi * 8;
  const float* bp32 = Wf + (size_t)(n0 + ln) * Hh + hi * 8;

  for (int kt = 0; kt < 16; ++kt) {
    short8 a[4], b[4];
#pragma unroll
    for (int mi = 0; mi < 4; ++mi)
      a[mi] = *(const short8*)(ap + (size_t)mi * 16 * Hh + kt * 32);
#pragma unroll
    for (int ni = 0; ni < 4; ++ni) {
      if (BF16W) {
        b[ni] = *(const short8*)(bp16 + (size_t)ni * 16 * Hh + kt * 32);
      } else {
        const float* q = bp32 + (size_t)ni * 16 * Hh + kt * 32;
        short8 tv;
#pragma unroll
        for (int e = 0; e < 8; ++e) tv[e] = (short)f2bf(q[e]);
        b[ni] = tv;
      }
    }
#pragma unroll
    for (int mi = 0; mi < 4; ++mi)
#pragma unroll
      for (int ni = 0; ni < 4; ++ni)
        acc[mi][ni] = __builtin_amdgcn_mfma_f32_16x16x32_bf16(a[mi], b[ni], acc[mi][ni], 0, 0, 0);
  }

#pragma unroll
  for (int ni = 0; ni < 4; ++ni) {
    int n = n0 + ni * 16 + ln;
    float bv = bias[n];
#pragma unroll
    for (int mi = 0; mi < 4; ++mi) {
      int mbase = m0 + mi * 16 + hi * 4;
#pragma unroll
      for (int r = 0; r < 4; ++r) {
        int m = mbase + r;
        if (m < 2032) {
          int t = m >> 4, bb = m & 15;
          out[((size_t)(bb * Tt + 1 + t)) * Vv + n] = acc[mi][ni][r] + bv;
        }
      }
    }
  }
}

extern "C" void kernel_launch(void* const* d_in, const int* in_sizes, int n_in,
                              void* d_out, int out_size, void* d_ws, size_t ws_size,
                              hipStream_t stream) {
  const int* x = (const int*)d_in[0];
  const float* enc_emb = (const float*)d_in[1];
  const float* enc_Wih = (const float*)d_in[2];
  const float* enc_bih = (const float*)d_in[3];
  const float* enc_Whh = (const float*)d_in[4];
  const float* enc_bhh = (const float*)d_in[5];
  const float* fc_enc_W = (const float*)d_in[6];
  const float* fc_enc_b = (const float*)d_in[7];
  const float* fc_dec_W = (const float*)d_in[8];
  const float* fc_dec_b = (const float*)d_in[9];
  const float* dec_emb = (const float*)d_in[10];
  const float* dec_Wih = (const float*)d_in[11];
  const float* dec_bih = (const float*)d_in[12];
  const float* dec_Whh = (const float*)d_in[13];
  const float* dec_bhh = (const float*)d_in[14];
  const float* dec_fcW = (const float*)d_in[15];
  const float* dec_fcb = (const float*)d_in[16];
  float* out = (float*)d_out;

  float* ws = (float*)d_ws;
  size_t off = 0;
  float* wihT_e = ws + off; off += 393216;
  float* wihT_d = ws + off; off += 393216;
  float* gx_e = ws + off; off += 3145728;
  float* gx_d = ws + off; off += 3121152;
  float* hbuf = ws + off; off += 16384;
  float* zbuf = ws + off; off += 2048;
  int* ctrl = (int*)(ws + off); off += 2048;  // flg_e[16*64] flg_d[16*64]
  int* flg_e = ctrl;
  int* flg_d = ctrl + 1024;
  unsigned short* hseq_bf = (unsigned short*)(ws + off); off += 524288;
  size_t wbf_elems = (size_t)Vv * Hh;
  bool use_wbf = (off + wbf_elems / 2) * sizeof(float) <= ws_size;
  unsigned short* wbf = (unsigned short*)(ws + off);

  // init
  hipMemsetAsync(ctrl, 0, 2048 * sizeof(int), stream);
  k_zero<<<(Bb * Hh + 255) / 256, 256, 0, stream>>>(hbuf, Bb * Hh);
  k_zero_first<<<(Bb * Vv + 255) / 256, 256, 0, stream>>>(out);

  if (use_wbf)
    k_cvt_bf16<<<(int)((wbf_elems / 4 + 255) / 256), 256, 0, stream>>>(
        dec_fcW, wbf, (int)(wbf_elems / 4));

  dim3 tb(32, 8);
  k_transpose<<<dim3(256 / 32, 1536 / 32), tb, 0, stream>>>(enc_Wih, wihT_e, 1536, 256);
  k_transpose<<<dim3(256 / 32, 1536 / 32), tb, 0, stream>>>(dec_Wih, wihT_d, 1536, 256);

  // gx_e (decoder gx fused into the encoder-scan launch)
  k_gx<<<128 * 6, 256, 0, stream>>>(x, enc_emb, wihT_e, enc_bih, gx_e);

  // encoder scan (256 WGs, 16 groups) + gx_d (762 WGs)
  k_enc_fused<<<NSW + 762, 256, 0, stream>>>(enc_Whh, enc_bhh, gx_e, hbuf, flg_e,
                                             x, dec_emb, wihT_d, dec_bih, gx_d);

  k_z<<<16, 128, 0, stream>>>(hbuf, fc_enc_W, fc_enc_b, zbuf, out + (size_t)Bb * Tt * Vv);
  k_hid0<<<16, 512, 0, stream>>>(zbuf, fc_dec_W, fc_dec_b, hbuf);

  // decoder scan (standalone, 16 groups)
  k_dec_scan<<<NSW, 256, 0, stream>>>(dec_Whh, dec_bhh, gx_d, hbuf, hseq_bf, flg_d);

  // logits (standalone)
  if (use_wbf)
    k_logits_mfma<true><<<dim3(Vv / 64, 8), 256, 0, stream>>>(hseq_bf, wbf, dec_fcW,
                                                              dec_fcb, out);
  else
    k_logits_mfma<false><<<dim3(Vv / 64, 8), 256, 0, stream>>>(hseq_bf, (unsigned short*)nullptr,
                                                               dec_fcW, dec_fcb, out);
}

// Round 12
// 860.739 us; speedup vs baseline: 2.5041x; 1.2539x over previous
//
#include <hip/hip_runtime.h>

#define Vv 32000
#define Ee 256
#define Hh 512
#define Ll 128
#define Bb 16
#define Tt 128
#define G3 1536   // 3*H
#define NSW 256   // scan WGs: 16 groups x 16 WGs
#define NPAIRB (Bb * Hh)  // pairs per buffer

typedef __attribute__((ext_vector_type(8))) short short8;
typedef __attribute__((ext_vector_type(4))) float f32x4;

__device__ __forceinline__ float sigmoidf_(float x) { return 1.f / (1.f + __expf(-x)); }

__device__ __forceinline__ unsigned short f2bf(float f) {
  unsigned int u = __float_as_uint(f);
  u = (u + 0x7fffu + ((u >> 16) & 1u)) >> 16;
  return (unsigned short)u;
}

// ---------------- small helpers ----------------
__global__ void k_zero_first(float* __restrict__ out) {
  int idx = blockIdx.x * 256 + threadIdx.x;
  if (idx < Bb * Vv) {
    int b = idx / Vv, v = idx % Vv;
    out[(size_t)b * Tt * Vv + v] = 0.f;
  }
}

__global__ void k_cvt_bf16(const float* __restrict__ in, unsigned short* __restrict__ out,
                           int n4) {
  int i = blockIdx.x * 256 + threadIdx.x;
  if (i < n4) {
    float4 v = ((const float4*)in)[i];
    ushort4 o;
    o.x = f2bf(v.x); o.y = f2bf(v.y); o.z = f2bf(v.z); o.w = f2bf(v.w);
    ((ushort4*)out)[i] = o;
  }
}

__global__ void k_transpose(const float* __restrict__ in, float* __restrict__ out,
                            int R, int C) {
  __shared__ float tile[32][33];
  int c = blockIdx.x * 32 + threadIdx.x;
  int r0 = blockIdx.y * 32;
  for (int i = threadIdx.y; i < 32; i += 8)
    tile[i][threadIdx.x] = in[(size_t)(r0 + i) * C + c];
  __syncthreads();
  int r = r0 + threadIdx.x;
  int c0 = blockIdx.x * 32;
  for (int i = threadIdx.y; i < 32; i += 8)
    out[(size_t)(c0 + i) * R + r] = tile[threadIdx.x][i];
}

// ---------------- gx body ----------------
__device__ __forceinline__ void gx_body(int e, const int* __restrict__ x,
                                        const float* __restrict__ emb,
                                        const float* __restrict__ WihT,
                                        const float* __restrict__ b_ih,
                                        float* __restrict__ gx) {
  __shared__ float A[16][Ee];
  int mt = e / 6, gy = e % 6;
  int g = gy * 256 + threadIdx.x;
  for (int i = 0; i < 16; i++) {
    int tok = x[i * Tt + mt];
    A[i][threadIdx.x] = emb[(size_t)tok * Ee + threadIdx.x];
  }
  __syncthreads();
  float acc[16];
  float bg = b_ih[g];
#pragma unroll
  for (int i = 0; i < 16; i++) acc[i] = bg;
#pragma unroll 4
  for (int ee = 0; ee < Ee; ee++) {
    float w = WihT[(size_t)ee * G3 + g];
#pragma unroll
    for (int i = 0; i < 16; i++) acc[i] = fmaf(A[i][ee], w, acc[i]);
  }
#pragma unroll
  for (int i = 0; i < 16; i++)
    gx[(size_t)(mt * 16 + i) * G3 + g] = acc[i];
}

__global__ void k_gx(const int* __restrict__ x, const float* __restrict__ emb,
                     const float* __restrict__ WihT, const float* __restrict__ b_ih,
                     float* __restrict__ gx) {
  gx_body(blockIdx.x, x, emb, WihT, b_ih, gx);
}

// ---------------- scan body: data-is-flag pair exchange, per-batch groups ----------------
// 16 groups (1 batch each) x 16 WGs (32 cols each).
// pairs[2][Bb*Hh]: (f32 value, u32 epoch); h(s) of batch g at pairs[s&1][g*Hh + j], epoch s.
// Per step: each thread polls its 2 pairs (dwordx4 sc1) until epoch==t, stages to LDS,
// sync, compute (reg weights x LDS broadcast, wave shfl-reduce), gate lanes publish
// (value, t+1) via single 8B sc1 store. No counter, no flag, no writer drain.
template <bool HSEQ>
__device__ __forceinline__ void scan_body(
    const float* __restrict__ Whh, const float* __restrict__ bhh,
    const float* __restrict__ gx, uint2* __restrict__ pairs,
    unsigned short* __restrict__ hseq, int nsteps) {
  __shared__ float h_lds[Hh];   // this group's batch h
  const int tid = threadIdx.x;
  const int wg = blockIdx.x;
  const int g = wg >> 4;
  const int wgl = wg & 15;
  const int wave = tid >> 6;
  const int lane = tid & 63;
  const int cl = lane >> 3;    // 0..7
  const int ks = lane & 7;     // 0..7
  const int j = wgl * 32 + wave * 8 + cl;
  const bool gate = (ks == 0);

  // weights: 3 gates x 64 interleaved k in f32 regs
  float wr[64], wz[64], wn[64];
  {
    const float* R = Whh + (size_t)j * Hh + ks * 4;
    const float* Z = R + (size_t)Hh * Hh;
    const float* N = Z + (size_t)Hh * Hh;
#pragma unroll
    for (int q = 0; q < 16; ++q) {
      float4 a = *(const float4*)(R + q * 32);
      float4 b = *(const float4*)(Z + q * 32);
      float4 c = *(const float4*)(N + q * 32);
      wr[4*q] = a.x; wr[4*q+1] = a.y; wr[4*q+2] = a.z; wr[4*q+3] = a.w;
      wz[4*q] = b.x; wz[4*q+1] = b.y; wz[4*q+2] = b.z; wz[4*q+3] = b.w;
      wn[4*q] = c.x; wn[4*q+1] = c.y; wn[4*q+2] = c.z; wn[4*q+3] = c.w;
    }
  }
  float bhr = 0.f, bhz = 0.f, bhn = 0.f;
  if (gate) { bhr = bhh[j]; bhz = bhh[Hh + j]; bhn = bhh[2 * Hh + j]; }

  // gx for step 0 (gate lanes); row m = t*16 + g
  float xr = 0.f, xz = 0.f, xn = 0.f;
  if (gate) {
    const float* gp = gx + (size_t)g * G3 + j;
    xr = gp[0]; xz = gp[Hh]; xn = gp[2 * Hh];
  }

  for (int t = 0; t < nsteps; ++t) {
    // ---- poll + stage h(t): data IS the flag (one LLC RT) ----
    {
      const uint4* pp =
          (const uint4*)(pairs + (size_t)(t & 1) * NPAIRB + (size_t)g * Hh) + tid;
      const unsigned ep = (unsigned)t;
      uint4 v;
      for (int it = 0; it < 200000; ++it) {
        asm volatile("global_load_dwordx4 %0, %1, off sc1\n\ts_waitcnt vmcnt(0)"
                     : "=v"(v) : "v"(pp) : "memory");
        if (v.y == ep && v.w == ep) break;
      }
      *(float2*)&h_lds[2 * tid] =
          make_float2(__uint_as_float(v.x), __uint_as_float(v.z));
    }
    __syncthreads();

    // ---- per-lane partial dots (reg weights x LDS h broadcast) ----
    float aR = 0.f, aZ = 0.f, aN = 0.f;
    {
      const float* hb = h_lds + ks * 4;
#pragma unroll
      for (int q = 0; q < 16; ++q) {
        float4 hv = *(const float4*)(hb + q * 32);
        aR = fmaf(wr[4*q+0], hv.x, aR);
        aR = fmaf(wr[4*q+1], hv.y, aR);
        aR = fmaf(wr[4*q+2], hv.z, aR);
        aR = fmaf(wr[4*q+3], hv.w, aR);
        aZ = fmaf(wz[4*q+0], hv.x, aZ);
        aZ = fmaf(wz[4*q+1], hv.y, aZ);
        aZ = fmaf(wz[4*q+2], hv.z, aZ);
        aZ = fmaf(wz[4*q+3], hv.w, aZ);
        aN = fmaf(wn[4*q+0], hv.x, aN);
        aN = fmaf(wn[4*q+1], hv.y, aN);
        aN = fmaf(wn[4*q+2], hv.z, aN);
        aN = fmaf(wn[4*q+3], hv.w, aN);
      }
    }
    // ---- reduce over ks (lane bits 0..2), fully within wave ----
    aR += __shfl_xor(aR, 1, 64); aR += __shfl_xor(aR, 2, 64); aR += __shfl_xor(aR, 4, 64);
    aZ += __shfl_xor(aZ, 1, 64); aZ += __shfl_xor(aZ, 2, 64); aZ += __shfl_xor(aZ, 4, 64);
    aN += __shfl_xor(aN, 1, 64); aN += __shfl_xor(aN, 2, 64); aN += __shfl_xor(aN, 4, 64);

    // ---- gate finish + publish (value,epoch) as one 8B sc1 store ----
    if (gate) {
      float r = sigmoidf_(xr + aR + bhr);
      float u = sigmoidf_(xz + aZ + bhz);
      float n = tanhf(xn + r * (aN + bhn));
      float hold = h_lds[j];
      float hnew = (1.f - u) * n + u * hold;
      uint2 pv = make_uint2(__float_as_uint(hnew), (unsigned)(t + 1));
      uint2* dst = pairs + (size_t)((t + 1) & 1) * NPAIRB + (size_t)g * Hh + j;
      asm volatile("global_store_dwordx2 %0, %1, off sc1" : : "v"(dst), "v"(pv) : "memory");
      if (HSEQ) hseq[((size_t)t * Bb + g) * Hh + j] = f2bf(hnew);
      if (t + 1 < nsteps) {  // prefetch next step's gx (cached loads)
        const float* gp = gx + (size_t)((t + 1) * Bb + g) * G3 + j;
        xr = gp[0]; xz = gp[Hh]; xn = gp[2 * Hh];
      }
    }
    __syncthreads();   // protect h_lds before next staging overwrite
  }
}

// ---------------- fused enc kernel: scan + decoder gx ----------------
__global__ void __launch_bounds__(256, 1) k_enc_fused(
    const float* __restrict__ Whh, const float* __restrict__ bhh,
    const float* __restrict__ gx_e, uint2* __restrict__ pairs,
    const int* __restrict__ x, const float* __restrict__ dec_emb,
    const float* __restrict__ wihT_d, const float* __restrict__ dec_bih,
    float* __restrict__ gx_d) {
  if (blockIdx.x < NSW)
    scan_body<false>(Whh, bhh, gx_e, pairs, (unsigned short*)nullptr, Tt);
  else
    gx_body(blockIdx.x - NSW, x, dec_emb, wihT_d, dec_bih, gx_d);
}

// ---------------- standalone decoder scan ----------------
__global__ void __launch_bounds__(256, 1) k_dec_scan(
    const float* __restrict__ Whh, const float* __restrict__ bhh,
    const float* __restrict__ gx_d, uint2* __restrict__ pairs,
    unsigned short* __restrict__ hseq) {
  scan_body<true>(Whh, bhh, gx_d, pairs, hseq, Tt - 1);
}

// ---------------- fused z + hid0 (per-batch) ----------------
// block b: z[b] = h_last[b] @ fc_enc_W^T + b  (also output 2); hid0[b] -> dec pairs epoch 0
__global__ void k_zh(const uint2* __restrict__ hp,  // enc pairs buf0 (epoch 128)
                     const float* __restrict__ Wz, const float* __restrict__ bz,
                     float* __restrict__ zout,
                     const float* __restrict__ Wh, const float* __restrict__ bh,
                     uint2* __restrict__ hp0) {     // dec pairs buf0
  int b = blockIdx.x;
  int tid = threadIdx.x;  // 512
  __shared__ float hsh[Hh];
  __shared__ float zsh[Ll];
  hsh[tid] = __uint_as_float(hp[b * Hh + tid].x);
  __syncthreads();
  if (tid < Ll) {
    float acc = bz[tid];
#pragma unroll 4
    for (int k = 0; k < Hh; k++) acc = fmaf(hsh[k], Wz[(size_t)tid * Hh + k], acc);
    zsh[tid] = acc;
    zout[b * Ll + tid] = acc;
  }
  __syncthreads();
  float acc = bh[tid];
#pragma unroll 4
  for (int l = 0; l < Ll; l++) acc = fmaf(zsh[l], Wh[(size_t)tid * Ll + l], acc);
  hp0[b * Hh + tid] = make_uint2(__float_as_uint(tanhf(acc)), 0u);
}

// ---------------- logits via MFMA bf16 (standalone) ----------------
template <bool BF16W>
__global__ void __launch_bounds__(256) k_logits_mfma(
    const unsigned short* __restrict__ Abf,  // [2048][512] bf16
    const unsigned short* __restrict__ Wbf,  // [32000][512] bf16 (if BF16W)
    const float* __restrict__ Wf,            // [32000][512] f32 (fallback)
    const float* __restrict__ bias, float* __restrict__ out) {
  const int tid = threadIdx.x;
  const int wid = tid >> 6, lane = tid & 63;
  const int ln = lane & 15, hi = lane >> 4;
  const int n0 = blockIdx.x * 64;
  const int m0 = blockIdx.y * 256 + wid * 64;
  f32x4 acc[4][4];
#pragma unroll
  for (int mi = 0; mi < 4; ++mi)
#pragma unroll
    for (int ni = 0; ni < 4; ++ni) acc[mi][ni] = (f32x4)0.f;

  const unsigned short* ap = Abf + (size_t)(m0 + ln) * Hh + hi * 8;
  const unsigned short* bp16 = Wbf + (size_t)(n0 + ln) * Hh + hi * 8;
  const float* bp32 = Wf + (size_t)(n0 + ln) * Hh + hi * 8;

  for (int kt = 0; kt < 16; ++kt) {
    short8 a[4], b[4];
#pragma unroll
    for (int mi = 0; mi < 4; ++mi)
      a[mi] = *(const short8*)(ap + (size_t)mi * 16 * Hh + kt * 32);
#pragma unroll
    for (int ni = 0; ni < 4; ++ni) {
      if (BF16W) {
        b[ni] = *(const short8*)(bp16 + (size_t)ni * 16 * Hh + kt * 32);
      } else {
        const float* q = bp32 + (size_t)ni * 16 * Hh + kt * 32;
        short8 tv;
#pragma unroll
        for (int e = 0; e < 8; ++e) tv[e] = (short)f2bf(q[e]);
        b[ni] = tv;
      }
    }
#pragma unroll
    for (int mi = 0; mi < 4; ++mi)
#pragma unroll
      for (int ni = 0; ni < 4; ++ni)
        acc[mi][ni] = __builtin_amdgcn_mfma_f32_16x16x32_bf16(a[mi], b[ni], acc[mi][ni], 0, 0, 0);
  }

#pragma unroll
  for (int ni = 0; ni < 4; ++ni) {
    int n = n0 + ni * 16 + ln;
    float bv = bias[n];
#pragma unroll
    for (int mi = 0; mi < 4; ++mi) {
      int mbase = m0 + mi * 16 + hi * 4;
#pragma unroll
      for (int r = 0; r < 4; ++r) {
        int m = mbase + r;
        if (m < 2032) {
          int t = m >> 4, bb = m & 15;
          out[((size_t)(bb * Tt + 1 + t)) * Vv + n] = acc[mi][ni][r] + bv;
        }
      }
    }
  }
}

extern "C" void kernel_launch(void* const* d_in, const int* in_sizes, int n_in,
                              void* d_out, int out_size, void* d_ws, size_t ws_size,
                              hipStream_t stream) {
  const int* x = (const int*)d_in[0];
  const float* enc_emb = (const float*)d_in[1];
  const float* enc_Wih = (const float*)d_in[2];
  const float* enc_bih = (const float*)d_in[3];
  const float* enc_Whh = (const float*)d_in[4];
  const float* enc_bhh = (const float*)d_in[5];
  const float* fc_enc_W = (const float*)d_in[6];
  const float* fc_enc_b = (const float*)d_in[7];
  const float* fc_dec_W = (const float*)d_in[8];
  const float* fc_dec_b = (const float*)d_in[9];
  const float* dec_emb = (const float*)d_in[10];
  const float* dec_Wih = (const float*)d_in[11];
  const float* dec_bih = (const float*)d_in[12];
  const float* dec_Whh = (const float*)d_in[13];
  const float* dec_bhh = (const float*)d_in[14];
  const float* dec_fcW = (const float*)d_in[15];
  const float* dec_fcb = (const float*)d_in[16];
  float* out = (float*)d_out;

  float* ws = (float*)d_ws;
  size_t off = 0;
  float* wihT_e = ws + off; off += 393216;
  float* wihT_d = ws + off; off += 393216;
  float* gx_e = ws + off; off += 3145728;
  float* gx_d = ws + off; off += 3121152;
  uint2* enc_pairs = (uint2*)(ws + off); off += 4 * NPAIRB;  // [2][NPAIRB] uint2
  uint2* dec_pairs = (uint2*)(ws + off); off += 4 * NPAIRB;
  unsigned short* hseq_bf = (unsigned short*)(ws + off); off += 524288;
  size_t wbf_elems = (size_t)Vv * Hh;
  bool use_wbf = (off + wbf_elems / 2) * sizeof(float) <= ws_size;
  unsigned short* wbf = (unsigned short*)(ws + off);

  // init: all pair epochs/values -> 0 (enc h0 = 0 with epoch 0; stale epochs cleared
  // for graph replay), outputs[:,0,:] = 0
  hipMemsetAsync(enc_pairs, 0, 8 * NPAIRB * sizeof(uint2) / 2, stream);  // enc+dec contiguous
  k_zero_first<<<(Bb * Vv + 255) / 256, 256, 0, stream>>>(out);

  if (use_wbf)
    k_cvt_bf16<<<(int)((wbf_elems / 4 + 255) / 256), 256, 0, stream>>>(
        dec_fcW, wbf, (int)(wbf_elems / 4));

  dim3 tb(32, 8);
  k_transpose<<<dim3(256 / 32, 1536 / 32), tb, 0, stream>>>(enc_Wih, wihT_e, 1536, 256);
  k_transpose<<<dim3(256 / 32, 1536 / 32), tb, 0, stream>>>(dec_Wih, wihT_d, 1536, 256);

  // gx_e (decoder gx fused into the encoder-scan launch)
  k_gx<<<128 * 6, 256, 0, stream>>>(x, enc_emb, wihT_e, enc_bih, gx_e);

  // encoder scan (256 WGs, 16 groups) + gx_d (762 WGs)
  k_enc_fused<<<NSW + 762, 256, 0, stream>>>(enc_Whh, enc_bhh, gx_e, enc_pairs,
                                             x, dec_emb, wihT_d, dec_bih, gx_d);

  // z (output 2) + hid0 -> dec pairs buf0
  k_zh<<<16, 512, 0, stream>>>(enc_pairs, fc_enc_W, fc_enc_b,
                               out + (size_t)Bb * Tt * Vv, fc_dec_W, fc_dec_b, dec_pairs);

  // decoder scan
  k_dec_scan<<<NSW, 256, 0, stream>>>(dec_Whh, dec_bhh, gx_d, dec_pairs, hseq_bf);

  // logits
  if (use_wbf)
    k_logits_mfma<true><<<dim3(Vv / 64, 8), 256, 0, stream>>>(hseq_bf, wbf, dec_fcW,
                                                              dec_fcb, out);
  else
    k_logits_mfma<false><<<dim3(Vv / 64, 8), 256, 0, stream>>>(hseq_bf, (unsigned short*)nullptr,
                                                               dec_fcW, dec_fcb, out);
}

// Round 13
// 830.874 us; speedup vs baseline: 2.5942x; 1.0359x over previous
//
#include <hip/hip_runtime.h>

#define Vv 32000
#define Ee 256
#define Hh 512
#define Ll 128
#define Bb 16
#define Tt 128
#define G3 1536   // 3*H
#define NSW 256   // scan WGs: 16 groups x 16 WGs
#define NPAIRB (Bb * Hh)  // pairs per buffer

typedef __attribute__((ext_vector_type(8))) short short8;
typedef __attribute__((ext_vector_type(4))) float f32x4;

__device__ __forceinline__ float sigmoidf_(float x) { return 1.f / (1.f + __expf(-x)); }

__device__ __forceinline__ unsigned short f2bf(float f) {
  unsigned int u = __float_as_uint(f);
  u = (u + 0x7fffu + ((u >> 16) & 1u)) >> 16;
  return (unsigned short)u;
}

// ---------------- small helpers ----------------
__global__ void k_zero_first(float* __restrict__ out) {
  int idx = blockIdx.x * 256 + threadIdx.x;
  if (idx < Bb * Vv) {
    int b = idx / Vv, v = idx % Vv;
    out[(size_t)b * Tt * Vv + v] = 0.f;
  }
}

__global__ void k_cvt_bf16(const float* __restrict__ in, unsigned short* __restrict__ out,
                           int n4) {
  int i = blockIdx.x * 256 + threadIdx.x;
  if (i < n4) {
    float4 v = ((const float4*)in)[i];
    ushort4 o;
    o.x = f2bf(v.x); o.y = f2bf(v.y); o.z = f2bf(v.z); o.w = f2bf(v.w);
    ((ushort4*)out)[i] = o;
  }
}

__global__ void k_transpose(const float* __restrict__ in, float* __restrict__ out,
                            int R, int C) {
  __shared__ float tile[32][33];
  int c = blockIdx.x * 32 + threadIdx.x;
  int r0 = blockIdx.y * 32;
  for (int i = threadIdx.y; i < 32; i += 8)
    tile[i][threadIdx.x] = in[(size_t)(r0 + i) * C + c];
  __syncthreads();
  int r = r0 + threadIdx.x;
  int c0 = blockIdx.x * 32;
  for (int i = threadIdx.y; i < 32; i += 8)
    out[(size_t)(c0 + i) * R + r] = tile[threadIdx.x][i];
}

// ---------------- gx body ----------------
__device__ __forceinline__ void gx_body(int e, const int* __restrict__ x,
                                        const float* __restrict__ emb,
                                        const float* __restrict__ WihT,
                                        const float* __restrict__ b_ih,
                                        float* __restrict__ gx) {
  __shared__ float A[16][Ee];
  int mt = e / 6, gy = e % 6;
  int g = gy * 256 + threadIdx.x;
  for (int i = 0; i < 16; i++) {
    int tok = x[i * Tt + mt];
    A[i][threadIdx.x] = emb[(size_t)tok * Ee + threadIdx.x];
  }
  __syncthreads();
  float acc[16];
  float bg = b_ih[g];
#pragma unroll
  for (int i = 0; i < 16; i++) acc[i] = bg;
#pragma unroll 4
  for (int ee = 0; ee < Ee; ee++) {
    float w = WihT[(size_t)ee * G3 + g];
#pragma unroll
    for (int i = 0; i < 16; i++) acc[i] = fmaf(A[i][ee], w, acc[i]);
  }
#pragma unroll
  for (int i = 0; i < 16; i++)
    gx[(size_t)(mt * 16 + i) * G3 + g] = acc[i];
}

__global__ void k_gx(const int* __restrict__ x, const float* __restrict__ emb,
                     const float* __restrict__ WihT, const float* __restrict__ b_ih,
                     float* __restrict__ gx) {
  gx_body(blockIdx.x, x, emb, WihT, b_ih, gx);
}

// ---------------- scan body: data-is-flag pair exchange, per-batch groups ----------------
template <bool HSEQ>
__device__ __forceinline__ void scan_body(
    const float* __restrict__ Whh, const float* __restrict__ bhh,
    const float* __restrict__ gx, uint2* __restrict__ pairs,
    unsigned short* __restrict__ hseq, int nsteps) {
  __shared__ float h_lds[Hh];   // this group's batch h
  const int tid = threadIdx.x;
  const int wg = blockIdx.x;
  const int g = wg >> 4;
  const int wgl = wg & 15;
  const int wave = tid >> 6;
  const int lane = tid & 63;
  const int cl = lane >> 3;    // 0..7
  const int ks = lane & 7;     // 0..7
  const int j = wgl * 32 + wave * 8 + cl;
  const bool gate = (ks == 0);

  // weights: 3 gates x 64 interleaved k in f32 regs
  float wr[64], wz[64], wn[64];
  {
    const float* R = Whh + (size_t)j * Hh + ks * 4;
    const float* Z = R + (size_t)Hh * Hh;
    const float* N = Z + (size_t)Hh * Hh;
#pragma unroll
    for (int q = 0; q < 16; ++q) {
      float4 a = *(const float4*)(R + q * 32);
      float4 b = *(const float4*)(Z + q * 32);
      float4 c = *(const float4*)(N + q * 32);
      wr[4*q] = a.x; wr[4*q+1] = a.y; wr[4*q+2] = a.z; wr[4*q+3] = a.w;
      wz[4*q] = b.x; wz[4*q+1] = b.y; wz[4*q+2] = b.z; wz[4*q+3] = b.w;
      wn[4*q] = c.x; wn[4*q+1] = c.y; wn[4*q+2] = c.z; wn[4*q+3] = c.w;
    }
  }
  float bhr = 0.f, bhz = 0.f, bhn = 0.f;
  if (gate) { bhr = bhh[j]; bhz = bhh[Hh + j]; bhn = bhh[2 * Hh + j]; }

  float xr = 0.f, xz = 0.f, xn = 0.f;
  if (gate) {
    const float* gp = gx + (size_t)g * G3 + j;
    xr = gp[0]; xz = gp[Hh]; xn = gp[2 * Hh];
  }

  for (int t = 0; t < nsteps; ++t) {
    // ---- poll + stage h(t): data IS the flag (one LLC RT) ----
    {
      const uint4* pp =
          (const uint4*)(pairs + (size_t)(t & 1) * NPAIRB + (size_t)g * Hh) + tid;
      const unsigned ep = (unsigned)t;
      uint4 v;
      for (int it = 0; it < 200000; ++it) {
        asm volatile("global_load_dwordx4 %0, %1, off sc1\n\ts_waitcnt vmcnt(0)"
                     : "=v"(v) : "v"(pp) : "memory");
        if (v.y == ep && v.w == ep) break;
      }
      *(float2*)&h_lds[2 * tid] =
          make_float2(__uint_as_float(v.x), __uint_as_float(v.z));
    }
    __syncthreads();

    // ---- per-lane partial dots (reg weights x LDS h broadcast) ----
    float aR = 0.f, aZ = 0.f, aN = 0.f;
    {
      const float* hb = h_lds + ks * 4;
#pragma unroll
      for (int q = 0; q < 16; ++q) {
        float4 hv = *(const float4*)(hb + q * 32);
        aR = fmaf(wr[4*q+0], hv.x, aR);
        aR = fmaf(wr[4*q+1], hv.y, aR);
        aR = fmaf(wr[4*q+2], hv.z, aR);
        aR = fmaf(wr[4*q+3], hv.w, aR);
        aZ = fmaf(wz[4*q+0], hv.x, aZ);
        aZ = fmaf(wz[4*q+1], hv.y, aZ);
        aZ = fmaf(wz[4*q+2], hv.z, aZ);
        aZ = fmaf(wz[4*q+3], hv.w, aZ);
        aN = fmaf(wn[4*q+0], hv.x, aN);
        aN = fmaf(wn[4*q+1], hv.y, aN);
        aN = fmaf(wn[4*q+2], hv.z, aN);
        aN = fmaf(wn[4*q+3], hv.w, aN);
      }
    }
    aR += __shfl_xor(aR, 1, 64); aR += __shfl_xor(aR, 2, 64); aR += __shfl_xor(aR, 4, 64);
    aZ += __shfl_xor(aZ, 1, 64); aZ += __shfl_xor(aZ, 2, 64); aZ += __shfl_xor(aZ, 4, 64);
    aN += __shfl_xor(aN, 1, 64); aN += __shfl_xor(aN, 2, 64); aN += __shfl_xor(aN, 4, 64);

    if (gate) {
      float r = sigmoidf_(xr + aR + bhr);
      float u = sigmoidf_(xz + aZ + bhz);
      float n = tanhf(xn + r * (aN + bhn));
      float hold = h_lds[j];
      float hnew = (1.f - u) * n + u * hold;
      uint2 pv = make_uint2(__float_as_uint(hnew), (unsigned)(t + 1));
      uint2* dst = pairs + (size_t)((t + 1) & 1) * NPAIRB + (size_t)g * Hh + j;
      asm volatile("global_store_dwordx2 %0, %1, off sc1" : : "v"(dst), "v"(pv) : "memory");
      if (HSEQ) hseq[((size_t)t * Bb + g) * Hh + j] = f2bf(hnew);
      if (t + 1 < nsteps) {
        const float* gp = gx + (size_t)((t + 1) * Bb + g) * G3 + j;
        xr = gp[0]; xz = gp[Hh]; xn = gp[2 * Hh];
      }
    }
    __syncthreads();   // protect h_lds before next staging overwrite
  }
}

// ---------------- fused enc kernel: scan + decoder gx ----------------
__global__ void __launch_bounds__(256, 1) k_enc_fused(
    const float* __restrict__ Whh, const float* __restrict__ bhh,
    const float* __restrict__ gx_e, uint2* __restrict__ pairs,
    const int* __restrict__ x, const float* __restrict__ dec_emb,
    const float* __restrict__ wihT_d, const float* __restrict__ dec_bih,
    float* __restrict__ gx_d) {
  if (blockIdx.x < NSW)
    scan_body<false>(Whh, bhh, gx_e, pairs, (unsigned short*)nullptr, Tt);
  else
    gx_body(blockIdx.x - NSW, x, dec_emb, wihT_d, dec_bih, gx_d);
}

// ---------------- standalone decoder scan ----------------
__global__ void __launch_bounds__(256, 1) k_dec_scan(
    const float* __restrict__ Whh, const float* __restrict__ bhh,
    const float* __restrict__ gx_d, uint2* __restrict__ pairs,
    unsigned short* __restrict__ hseq) {
  scan_body<true>(Whh, bhh, gx_d, pairs, hseq, Tt - 1);
}

// ---------------- fused z + hid0 (per-batch) ----------------
__global__ void k_zh(const uint2* __restrict__ hp,
                     const float* __restrict__ Wz, const float* __restrict__ bz,
                     float* __restrict__ zout,
                     const float* __restrict__ Wh, const float* __restrict__ bh,
                     uint2* __restrict__ hp0) {
  int b = blockIdx.x;
  int tid = threadIdx.x;  // 512
  __shared__ float hsh[Hh];
  __shared__ float zsh[Ll];
  hsh[tid] = __uint_as_float(hp[b * Hh + tid].x);
  __syncthreads();
  if (tid < Ll) {
    float acc = bz[tid];
#pragma unroll 4
    for (int k = 0; k < Hh; k++) acc = fmaf(hsh[k], Wz[(size_t)tid * Hh + k], acc);
    zsh[tid] = acc;
    zout[b * Ll + tid] = acc;
  }
  __syncthreads();
  float acc = bh[tid];
#pragma unroll 4
  for (int l = 0; l < Ll; l++) acc = fmaf(zsh[l], Wh[(size_t)tid * Ll + l], acc);
  hp0[b * Hh + tid] = make_uint2(__float_as_uint(tanhf(acc)), 0u);
}

// ---------------- logits via MFMA bf16, swapped operands + nt stores ----------------
// A-op := W rows (n), B-op := hs rows (m)  =>  D[row=n][col=m]:
// lane holds col m = m0+mi*16+(lane&15); rows n = n0+ni*16+(lane>>4)*4+reg (4 consecutive n)
// -> one dwordx4 non-temporal store per (mi,ni): contiguous in out's fast axis.
template <bool BF16W>
__global__ void __launch_bounds__(256) k_logits_mfma(
    const unsigned short* __restrict__ Abf,  // hs [2048][512] bf16
    const unsigned short* __restrict__ Wbf,  // [32000][512] bf16 (if BF16W)
    const float* __restrict__ Wf,            // [32000][512] f32 (fallback)
    const float* __restrict__ bias, float* __restrict__ out) {
  const int tid = threadIdx.x;
  const int wid = tid >> 6, lane = tid & 63;
  const int ln = lane & 15, hi = lane >> 4;
  const int n0 = blockIdx.x * 64;
  const int m0 = blockIdx.y * 256 + wid * 64;
  f32x4 acc[4][4];  // [mi][ni]
#pragma unroll
  for (int mi = 0; mi < 4; ++mi)
#pragma unroll
    for (int ni = 0; ni < 4; ++ni) acc[mi][ni] = (f32x4)0.f;

  const unsigned short* hp = Abf + (size_t)(m0 + ln) * Hh + hi * 8;
  const unsigned short* wp16 = BF16W ? (Wbf + (size_t)(n0 + ln) * Hh + hi * 8) : nullptr;
  const float* wp32 = BF16W ? nullptr : (Wf + (size_t)(n0 + ln) * Hh + hi * 8);

  for (int kt = 0; kt < 16; ++kt) {
    short8 aW[4], bH[4];
#pragma unroll
    for (int ni = 0; ni < 4; ++ni) {
      if (BF16W) {
        aW[ni] = *(const short8*)(wp16 + (size_t)ni * 16 * Hh + kt * 32);
      } else {
        const float* q = wp32 + (size_t)ni * 16 * Hh + kt * 32;
        short8 tv;
#pragma unroll
        for (int e = 0; e < 8; ++e) tv[e] = (short)f2bf(q[e]);
        aW[ni] = tv;
      }
    }
#pragma unroll
    for (int mi = 0; mi < 4; ++mi)
      bH[mi] = *(const short8*)(hp + (size_t)mi * 16 * Hh + kt * 32);
#pragma unroll
    for (int mi = 0; mi < 4; ++mi)
#pragma unroll
      for (int ni = 0; ni < 4; ++ni)
        acc[mi][ni] = __builtin_amdgcn_mfma_f32_16x16x32_bf16(aW[ni], bH[mi], acc[mi][ni], 0, 0, 0);
  }

#pragma unroll
  for (int ni = 0; ni < 4; ++ni) {
    const int n = n0 + ni * 16 + hi * 4;
    const f32x4 bv = *(const f32x4*)&bias[n];
#pragma unroll
    for (int mi = 0; mi < 4; ++mi) {
      int m = m0 + mi * 16 + ln;
      if (m < 2032) {
        int t = m >> 4, bb = m & 15;
        float* dst = out + ((size_t)(bb * Tt + 1 + t)) * Vv + n;
        f32x4 o = acc[mi][ni] + bv;
        __builtin_nontemporal_store(o, (f32x4*)dst);
      }
    }
  }
}

extern "C" void kernel_launch(void* const* d_in, const int* in_sizes, int n_in,
                              void* d_out, int out_size, void* d_ws, size_t ws_size,
                              hipStream_t stream) {
  const int* x = (const int*)d_in[0];
  const float* enc_emb = (const float*)d_in[1];
  const float* enc_Wih = (const float*)d_in[2];
  const float* enc_bih = (const float*)d_in[3];
  const float* enc_Whh = (const float*)d_in[4];
  const float* enc_bhh = (const float*)d_in[5];
  const float* fc_enc_W = (const float*)d_in[6];
  const float* fc_enc_b = (const float*)d_in[7];
  const float* fc_dec_W = (const float*)d_in[8];
  const float* fc_dec_b = (const float*)d_in[9];
  const float* dec_emb = (const float*)d_in[10];
  const float* dec_Wih = (const float*)d_in[11];
  const float* dec_bih = (const float*)d_in[12];
  const float* dec_Whh = (const float*)d_in[13];
  const float* dec_bhh = (const float*)d_in[14];
  const float* dec_fcW = (const float*)d_in[15];
  const float* dec_fcb = (const float*)d_in[16];
  float* out = (float*)d_out;

  float* ws = (float*)d_ws;
  size_t off = 0;
  float* wihT_e = ws + off; off += 393216;
  float* wihT_d = ws + off; off += 393216;
  float* gx_e = ws + off; off += 3145728;
  float* gx_d = ws + off; off += 3121152;
  uint2* enc_pairs = (uint2*)(ws + off); off += 4 * NPAIRB;
  uint2* dec_pairs = (uint2*)(ws + off); off += 4 * NPAIRB;
  unsigned short* hseq_bf = (unsigned short*)(ws + off); off += 524288;
  size_t wbf_elems = (size_t)Vv * Hh;
  bool use_wbf = (off + wbf_elems / 2) * sizeof(float) <= ws_size;
  unsigned short* wbf = (unsigned short*)(ws + off);

  // init: pair buffers zeroed (enc h0 = 0 @ epoch 0; stale epochs cleared), out[:,0,:]=0
  hipMemsetAsync(enc_pairs, 0, 8 * NPAIRB * sizeof(uint2) / 2, stream);
  k_zero_first<<<(Bb * Vv + 255) / 256, 256, 0, stream>>>(out);

  if (use_wbf)
    k_cvt_bf16<<<(int)((wbf_elems / 4 + 255) / 256), 256, 0, stream>>>(
        dec_fcW, wbf, (int)(wbf_elems / 4));

  dim3 tb(32, 8);
  k_transpose<<<dim3(256 / 32, 1536 / 32), tb, 0, stream>>>(enc_Wih, wihT_e, 1536, 256);
  k_transpose<<<dim3(256 / 32, 1536 / 32), tb, 0, stream>>>(dec_Wih, wihT_d, 1536, 256);

  // gx_e (decoder gx fused into the encoder-scan launch)
  k_gx<<<128 * 6, 256, 0, stream>>>(x, enc_emb, wihT_e, enc_bih, gx_e);

  // encoder scan (256 WGs, 16 groups) + gx_d (762 WGs)
  k_enc_fused<<<NSW + 762, 256, 0, stream>>>(enc_Whh, enc_bhh, gx_e, enc_pairs,
                                             x, dec_emb, wihT_d, dec_bih, gx_d);

  // z (output 2) + hid0 -> dec pairs buf0
  k_zh<<<16, 512, 0, stream>>>(enc_pairs, fc_enc_W, fc_enc_b,
                               out + (size_t)Bb * Tt * Vv, fc_dec_W, fc_dec_b, dec_pairs);

  // decoder scan
  k_dec_scan<<<NSW, 256, 0, stream>>>(dec_Whh, dec_bhh, gx_d, dec_pairs, hseq_bf);

  // logits
  if (use_wbf)
    k_logits_mfma<true><<<dim3(Vv / 64, 8), 256, 0, stream>>>(hseq_bf, wbf, dec_fcW,
                                                              dec_fcb, out);
  else
    k_logits_mfma<false><<<dim3(Vv / 64, 8), 256, 0, stream>>>(hseq_bf, (unsigned short*)nullptr,
                                                               dec_fcW, dec_fcb, out);
}

// Round 14
// 703.291 us; speedup vs baseline: 3.0648x; 1.1814x over previous
//
#include <hip/hip_runtime.h>

#define Vv 32000
#define Ee 256
#define Hh 512
#define Ll 128
#define Bb 16
#define Tt 128
#define G3 1536   // 3*H
#define NSW 256   // scan WGs: 16 groups x 16 WGs
#define NPAIRB (Bb * Hh)  // pairs per buffer

typedef __attribute__((ext_vector_type(8))) short short8;
typedef __attribute__((ext_vector_type(4))) float f32x4;

__device__ __forceinline__ float sigmoidf_(float x) { return 1.f / (1.f + __expf(-x)); }

__device__ __forceinline__ unsigned short f2bf(float f) {
  unsigned int u = __float_as_uint(f);
  u = (u + 0x7fffu + ((u >> 16) & 1u)) >> 16;
  return (unsigned short)u;
}

// ---------------- small helpers ----------------
__global__ void k_zero_first(float* __restrict__ out) {
  int idx = blockIdx.x * 256 + threadIdx.x;
  if (idx < Bb * Vv) {
    int b = idx / Vv, v = idx % Vv;
    out[(size_t)b * Tt * Vv + v] = 0.f;
  }
}

__global__ void k_cvt_bf16(const float* __restrict__ in, unsigned short* __restrict__ out,
                           int n4) {
  int i = blockIdx.x * 256 + threadIdx.x;
  if (i < n4) {
    float4 v = ((const float4*)in)[i];
    ushort4 o;
    o.x = f2bf(v.x); o.y = f2bf(v.y); o.z = f2bf(v.z); o.w = f2bf(v.w);
    ((ushort4*)out)[i] = o;
  }
}

__global__ void k_transpose(const float* __restrict__ in, float* __restrict__ out,
                            int R, int C) {
  __shared__ float tile[32][33];
  int c = blockIdx.x * 32 + threadIdx.x;
  int r0 = blockIdx.y * 32;
  for (int i = threadIdx.y; i < 32; i += 8)
    tile[i][threadIdx.x] = in[(size_t)(r0 + i) * C + c];
  __syncthreads();
  int r = r0 + threadIdx.x;
  int c0 = blockIdx.x * 32;
  for (int i = threadIdx.y; i < 32; i += 8)
    out[(size_t)(c0 + i) * R + r] = tile[threadIdx.x][i];
}

// ---------------- gx body ----------------
__device__ __forceinline__ void gx_body(int e, const int* __restrict__ x,
                                        const float* __restrict__ emb,
                                        const float* __restrict__ WihT,
                                        const float* __restrict__ b_ih,
                                        float* __restrict__ gx) {
  __shared__ float A[16][Ee];
  int mt = e / 6, gy = e % 6;
  int g = gy * 256 + threadIdx.x;
  for (int i = 0; i < 16; i++) {
    int tok = x[i * Tt + mt];
    A[i][threadIdx.x] = emb[(size_t)tok * Ee + threadIdx.x];
  }
  __syncthreads();
  float acc[16];
  float bg = b_ih[g];
#pragma unroll
  for (int i = 0; i < 16; i++) acc[i] = bg;
#pragma unroll 4
  for (int ee = 0; ee < Ee; ee++) {
    float w = WihT[(size_t)ee * G3 + g];
#pragma unroll
    for (int i = 0; i < 16; i++) acc[i] = fmaf(A[i][ee], w, acc[i]);
  }
#pragma unroll
  for (int i = 0; i < 16; i++)
    gx[(size_t)(mt * 16 + i) * G3 + g] = acc[i];
}

__global__ void k_gx(const int* __restrict__ x, const float* __restrict__ emb,
                     const float* __restrict__ WihT, const float* __restrict__ b_ih,
                     float* __restrict__ gx) {
  gx_body(blockIdx.x, x, emb, WihT, b_ih, gx);
}

// ---------------- scan body: data-is-flag pair exchange, per-batch groups ----------------
template <bool HSEQ>
__device__ __forceinline__ void scan_body(
    const float* __restrict__ Whh, const float* __restrict__ bhh,
    const float* __restrict__ gx, uint2* __restrict__ pairs,
    unsigned short* __restrict__ hseq, int nsteps) {
  __shared__ float h_lds[Hh];   // this group's batch h
  const int tid = threadIdx.x;
  const int wg = blockIdx.x;
  const int g = wg >> 4;
  const int wgl = wg & 15;
  const int wave = tid >> 6;
  const int lane = tid & 63;
  const int cl = lane >> 3;    // 0..7
  const int ks = lane & 7;     // 0..7
  const int j = wgl * 32 + wave * 8 + cl;
  const bool gate = (ks == 0);

  // weights: 3 gates x 64 interleaved k in f32 regs
  float wr[64], wz[64], wn[64];
  {
    const float* R = Whh + (size_t)j * Hh + ks * 4;
    const float* Z = R + (size_t)Hh * Hh;
    const float* N = Z + (size_t)Hh * Hh;
#pragma unroll
    for (int q = 0; q < 16; ++q) {
      float4 a = *(const float4*)(R + q * 32);
      float4 b = *(const float4*)(Z + q * 32);
      float4 c = *(const float4*)(N + q * 32);
      wr[4*q] = a.x; wr[4*q+1] = a.y; wr[4*q+2] = a.z; wr[4*q+3] = a.w;
      wz[4*q] = b.x; wz[4*q+1] = b.y; wz[4*q+2] = b.z; wz[4*q+3] = b.w;
      wn[4*q] = c.x; wn[4*q+1] = c.y; wn[4*q+2] = c.z; wn[4*q+3] = c.w;
    }
  }
  float bhr = 0.f, bhz = 0.f, bhn = 0.f;
  if (gate) { bhr = bhh[j]; bhz = bhh[Hh + j]; bhn = bhh[2 * Hh + j]; }

  float xr = 0.f, xz = 0.f, xn = 0.f;
  if (gate) {
    const float* gp = gx + (size_t)g * G3 + j;
    xr = gp[0]; xz = gp[Hh]; xn = gp[2 * Hh];
  }

  for (int t = 0; t < nsteps; ++t) {
    // ---- poll + stage h(t): data IS the flag (one LLC RT) ----
    {
      const uint4* pp =
          (const uint4*)(pairs + (size_t)(t & 1) * NPAIRB + (size_t)g * Hh) + tid;
      const unsigned ep = (unsigned)t;
      uint4 v;
      for (int it = 0; it < 200000; ++it) {
        asm volatile("global_load_dwordx4 %0, %1, off sc1\n\ts_waitcnt vmcnt(0)"
                     : "=v"(v) : "v"(pp) : "memory");
        if (v.y == ep && v.w == ep) break;
      }
      *(float2*)&h_lds[2 * tid] =
          make_float2(__uint_as_float(v.x), __uint_as_float(v.z));
    }
    __syncthreads();

    // ---- per-lane partial dots (reg weights x LDS h broadcast) ----
    float aR = 0.f, aZ = 0.f, aN = 0.f;
    {
      const float* hb = h_lds + ks * 4;
#pragma unroll
      for (int q = 0; q < 16; ++q) {
        float4 hv = *(const float4*)(hb + q * 32);
        aR = fmaf(wr[4*q+0], hv.x, aR);
        aR = fmaf(wr[4*q+1], hv.y, aR);
        aR = fmaf(wr[4*q+2], hv.z, aR);
        aR = fmaf(wr[4*q+3], hv.w, aR);
        aZ = fmaf(wz[4*q+0], hv.x, aZ);
        aZ = fmaf(wz[4*q+1], hv.y, aZ);
        aZ = fmaf(wz[4*q+2], hv.z, aZ);
        aZ = fmaf(wz[4*q+3], hv.w, aZ);
        aN = fmaf(wn[4*q+0], hv.x, aN);
        aN = fmaf(wn[4*q+1], hv.y, aN);
        aN = fmaf(wn[4*q+2], hv.z, aN);
        aN = fmaf(wn[4*q+3], hv.w, aN);
      }
    }
    aR += __shfl_xor(aR, 1, 64); aR += __shfl_xor(aR, 2, 64); aR += __shfl_xor(aR, 4, 64);
    aZ += __shfl_xor(aZ, 1, 64); aZ += __shfl_xor(aZ, 2, 64); aZ += __shfl_xor(aZ, 4, 64);
    aN += __shfl_xor(aN, 1, 64); aN += __shfl_xor(aN, 2, 64); aN += __shfl_xor(aN, 4, 64);

    if (gate) {
      float r = sigmoidf_(xr + aR + bhr);
      float u = sigmoidf_(xz + aZ + bhz);
      float n = tanhf(xn + r * (aN + bhn));
      float hold = h_lds[j];
      float hnew = (1.f - u) * n + u * hold;
      uint2 pv = make_uint2(__float_as_uint(hnew), (unsigned)(t + 1));
      uint2* dst = pairs + (size_t)((t + 1) & 1) * NPAIRB + (size_t)g * Hh + j;
      asm volatile("global_store_dwordx2 %0, %1, off sc1" : : "v"(dst), "v"(pv) : "memory");
      if (HSEQ) hseq[((size_t)t * Bb + g) * Hh + j] = f2bf(hnew);
      if (t + 1 < nsteps) {
        const float* gp = gx + (size_t)((t + 1) * Bb + g) * G3 + j;
        xr = gp[0]; xz = gp[Hh]; xn = gp[2 * Hh];
      }
    }
    __syncthreads();   // protect h_lds before next staging overwrite
  }
}

// ---------------- fused enc kernel: scan + decoder gx ----------------
__global__ void __launch_bounds__(256, 1) k_enc_fused(
    const float* __restrict__ Whh, const float* __restrict__ bhh,
    const float* __restrict__ gx_e, uint2* __restrict__ pairs,
    const int* __restrict__ x, const float* __restrict__ dec_emb,
    const float* __restrict__ wihT_d, const float* __restrict__ dec_bih,
    float* __restrict__ gx_d) {
  if (blockIdx.x < NSW)
    scan_body<false>(Whh, bhh, gx_e, pairs, (unsigned short*)nullptr, Tt);
  else
    gx_body(blockIdx.x - NSW, x, dec_emb, wihT_d, dec_bih, gx_d);
}

// ---------------- standalone decoder scan ----------------
__global__ void __launch_bounds__(256, 1) k_dec_scan(
    const float* __restrict__ Whh, const float* __restrict__ bhh,
    const float* __restrict__ gx_d, uint2* __restrict__ pairs,
    unsigned short* __restrict__ hseq) {
  scan_body<true>(Whh, bhh, gx_d, pairs, hseq, Tt - 1);
}

// ---------------- fused z + hid0 (per-batch) ----------------
__global__ void k_zh(const uint2* __restrict__ hp,
                     const float* __restrict__ Wz, const float* __restrict__ bz,
                     float* __restrict__ zout,
                     const float* __restrict__ Wh, const float* __restrict__ bh,
                     uint2* __restrict__ hp0) {
  int b = blockIdx.x;
  int tid = threadIdx.x;  // 512
  __shared__ float hsh[Hh];
  __shared__ float zsh[Ll];
  hsh[tid] = __uint_as_float(hp[b * Hh + tid].x);
  __syncthreads();
  if (tid < Ll) {
    float acc = bz[tid];
#pragma unroll 4
    for (int k = 0; k < Hh; k++) acc = fmaf(hsh[k], Wz[(size_t)tid * Hh + k], acc);
    zsh[tid] = acc;
    zout[b * Ll + tid] = acc;
  }
  __syncthreads();
  float acc = bh[tid];
#pragma unroll 4
  for (int l = 0; l < Ll; l++) acc = fmaf(zsh[l], Wh[(size_t)tid * Ll + l], acc);
  hp0[b * Hh + tid] = make_uint2(__float_as_uint(tanhf(acc)), 0u);
}

// ---------------- logits: W-stationary MFMA, W tile in LDS ----------------
// Grid: 500 WGs x 512 thr (8 waves). WG owns n-block (64 cols of W).
// LDS frag-order: 16B chunk f = kc*64 + row  (row=n-local 0..63, kc = kt*4+hi, k = kc*8).
// Stage: thread stages chunks f = tid + 512*c (ds_write contiguous, conflict-free).
// Inner: 4 passes x (wave = 64 m rows): aW from LDS, bH from global (L2-hot), MFMA.
// Epilogue: D[row=n][col=m] -> per (mi,ni) one dwordx4 nt store (4 consecutive n).
template <bool BF16W>
__global__ void __launch_bounds__(512, 1) k_logits_mfma(
    const unsigned short* __restrict__ Abf,  // hs [2048][512] bf16
    const unsigned short* __restrict__ Wbf,  // [32000][512] bf16 (if BF16W)
    const float* __restrict__ Wf,            // [32000][512] f32 (fallback)
    const float* __restrict__ bias, float* __restrict__ out) {
  __shared__ short W_lds[32768];  // 64 KB, frag-order
  const int tid = threadIdx.x;
  const int wave = tid >> 6, lane = tid & 63;
  const int ln = lane & 15, hi = lane >> 4;
  const int n0 = blockIdx.x * 64;

  // ---- stage W tile into LDS (frag order) ----
#pragma unroll
  for (int c = 0; c < 8; ++c) {
    int f = c * 512 + tid;       // chunk id = kc*64 + row
    int row = f & 63;
    int kc = f >> 6;             // 0..63
    short8 v;
    if (BF16W) {
      v = *(const short8*)(Wbf + (size_t)(n0 + row) * Hh + kc * 8);
    } else {
      const float* q = Wf + (size_t)(n0 + row) * Hh + kc * 8;
      short8 tv;
#pragma unroll
      for (int e = 0; e < 8; ++e) tv[e] = (short)f2bf(q[e]);
      v = tv;
    }
    *(short8*)&W_lds[f * 8] = v;
  }
  __syncthreads();

  // bias vectors per ni (n = n0 + ni*16 + hi*4)
  f32x4 bv[4];
#pragma unroll
  for (int ni = 0; ni < 4; ++ni)
    bv[ni] = *(const f32x4*)&bias[n0 + ni * 16 + hi * 4];

  for (int pass = 0; pass < 4; ++pass) {
    const int m0 = pass * 512 + wave * 64;
    const unsigned short* hp = Abf + (size_t)(m0 + ln) * Hh + hi * 8;
    f32x4 acc[4][4];  // [mi][ni]
#pragma unroll
    for (int mi = 0; mi < 4; ++mi)
#pragma unroll
      for (int ni = 0; ni < 4; ++ni) acc[mi][ni] = (f32x4)0.f;

    for (int kt = 0; kt < 16; ++kt) {
      short8 aW[4], bH[4];
#pragma unroll
      for (int ni = 0; ni < 4; ++ni)
        aW[ni] = *(const short8*)&W_lds[(((kt * 4 + hi) * 64) + ni * 16 + ln) * 8];
#pragma unroll
      for (int mi = 0; mi < 4; ++mi)
        bH[mi] = *(const short8*)(hp + (size_t)mi * 16 * Hh + kt * 32);
#pragma unroll
      for (int mi = 0; mi < 4; ++mi)
#pragma unroll
        for (int ni = 0; ni < 4; ++ni)
          acc[mi][ni] = __builtin_amdgcn_mfma_f32_16x16x32_bf16(aW[ni], bH[mi], acc[mi][ni], 0, 0, 0);
    }

#pragma unroll
    for (int ni = 0; ni < 4; ++ni) {
      const int n = n0 + ni * 16 + hi * 4;
#pragma unroll
      for (int mi = 0; mi < 4; ++mi) {
        int m = m0 + mi * 16 + ln;
        if (m < 2032) {
          int t = m >> 4, bb = m & 15;
          float* dst = out + ((size_t)(bb * Tt + 1 + t)) * Vv + n;
          f32x4 o = acc[mi][ni] + bv[ni];
          __builtin_nontemporal_store(o, (f32x4*)dst);
        }
      }
    }
  }
}

extern "C" void kernel_launch(void* const* d_in, const int* in_sizes, int n_in,
                              void* d_out, int out_size, void* d_ws, size_t ws_size,
                              hipStream_t stream) {
  const int* x = (const int*)d_in[0];
  const float* enc_emb = (const float*)d_in[1];
  const float* enc_Wih = (const float*)d_in[2];
  const float* enc_bih = (const float*)d_in[3];
  const float* enc_Whh = (const float*)d_in[4];
  const float* enc_bhh = (const float*)d_in[5];
  const float* fc_enc_W = (const float*)d_in[6];
  const float* fc_enc_b = (const float*)d_in[7];
  const float* fc_dec_W = (const float*)d_in[8];
  const float* fc_dec_b = (const float*)d_in[9];
  const float* dec_emb = (const float*)d_in[10];
  const float* dec_Wih = (const float*)d_in[11];
  const float* dec_bih = (const float*)d_in[12];
  const float* dec_Whh = (const float*)d_in[13];
  const float* dec_bhh = (const float*)d_in[14];
  const float* dec_fcW = (const float*)d_in[15];
  const float* dec_fcb = (const float*)d_in[16];
  float* out = (float*)d_out;

  float* ws = (float*)d_ws;
  size_t off = 0;
  float* wihT_e = ws + off; off += 393216;
  float* wihT_d = ws + off; off += 393216;
  float* gx_e = ws + off; off += 3145728;
  float* gx_d = ws + off; off += 3121152;
  uint2* enc_pairs = (uint2*)(ws + off); off += 4 * NPAIRB;
  uint2* dec_pairs = (uint2*)(ws + off); off += 4 * NPAIRB;
  unsigned short* hseq_bf = (unsigned short*)(ws + off); off += 524288;
  size_t wbf_elems = (size_t)Vv * Hh;
  bool use_wbf = (off + wbf_elems / 2) * sizeof(float) <= ws_size;
  unsigned short* wbf = (unsigned short*)(ws + off);

  // init: pair buffers zeroed (enc h0 = 0 @ epoch 0; stale epochs cleared), out[:,0,:]=0
  hipMemsetAsync(enc_pairs, 0, 8 * NPAIRB * sizeof(uint2) / 2, stream);
  k_zero_first<<<(Bb * Vv + 255) / 256, 256, 0, stream>>>(out);

  if (use_wbf)
    k_cvt_bf16<<<(int)((wbf_elems / 4 + 255) / 256), 256, 0, stream>>>(
        dec_fcW, wbf, (int)(wbf_elems / 4));

  dim3 tb(32, 8);
  k_transpose<<<dim3(256 / 32, 1536 / 32), tb, 0, stream>>>(enc_Wih, wihT_e, 1536, 256);
  k_transpose<<<dim3(256 / 32, 1536 / 32), tb, 0, stream>>>(dec_Wih, wihT_d, 1536, 256);

  // gx_e (decoder gx fused into the encoder-scan launch)
  k_gx<<<128 * 6, 256, 0, stream>>>(x, enc_emb, wihT_e, enc_bih, gx_e);

  // encoder scan (256 WGs, 16 groups) + gx_d (762 WGs)
  k_enc_fused<<<NSW + 762, 256, 0, stream>>>(enc_Whh, enc_bhh, gx_e, enc_pairs,
                                             x, dec_emb, wihT_d, dec_bih, gx_d);

  // z (output 2) + hid0 -> dec pairs buf0
  k_zh<<<16, 512, 0, stream>>>(enc_pairs, fc_enc_W, fc_enc_b,
                               out + (size_t)Bb * Tt * Vv, fc_dec_W, fc_dec_b, dec_pairs);

  // decoder scan
  k_dec_scan<<<NSW, 256, 0, stream>>>(dec_Whh, dec_bhh, gx_d, dec_pairs, hseq_bf);

  // logits (W-stationary, 500 WGs x 512 thr)
  if (use_wbf)
    k_logits_mfma<true><<<500, 512, 0, stream>>>(hseq_bf, wbf, dec_fcW, dec_fcb, out);
  else
    k_logits_mfma<false><<<500, 512, 0, stream>>>(hseq_bf, (unsigned short*)nullptr,
                                                  dec_fcW, dec_fcb, out);
}